// Round 1
// baseline (5060.716 us; speedup 1.0000x reference)
//
#include <hip/hip_runtime.h>
#include <hip/hip_bf16.h>
#include <math.h>

#define H_ 32
#define R_ 512
#define NOPE_ 128
#define ROPE_ 64
#define V_ 128
#define HID_ 4096
#define B_ 64
#define S_ 4096
#define TOPK_ 2048
#define DQ_ 192      // NOPE+ROPE
#define NQ_ 6144     // H*DQ
#define DKV_ 576     // R+ROPE
#define KCH_ 8       // K-chunks for partial skinny GEMMs
#define ACH_ 8       // attention k-chunks
#define CHUNK_ 256   // TOPK/ACH

__device__ __forceinline__ float4 ld4(const float* p) { return *reinterpret_cast<const float4*>(p); }

// ---------------- skinny partial GEMM: C_partial[kc] = A(64 x Kchunk) @ B ----------------
__global__ __launch_bounds__(256) void gemm64_partial(const float* __restrict__ A,
    const float* __restrict__ Bm, float* __restrict__ Cp, int N, int K) {
  // grid: (N/128, KCH_)
  __shared__ float xs[64*32];
  __shared__ float wsb[32*128];
  const int t = threadIdx.x;
  const int nt = blockIdx.x, kc = blockIdx.y;
  const int n0 = nt*128;
  const int kchunk = K / KCH_;
  const int kbeg = kc*kchunk;
  const int tr = t >> 5, tc = t & 31;
  float4 acc[8];
  #pragma unroll
  for (int i=0;i<8;i++) acc[i] = make_float4(0.f,0.f,0.f,0.f);
  for (int k0 = kbeg; k0 < kbeg + kchunk; k0 += 32) {
    #pragma unroll
    for (int l=0;l<2;l++) {
      int idx = t + l*256;
      int row = idx >> 3, c4 = idx & 7;
      *reinterpret_cast<float4*>(&xs[row*32 + c4*4]) = ld4(&A[(size_t)row*K + k0 + c4*4]);
    }
    #pragma unroll
    for (int l=0;l<4;l++) {
      int idx = t + l*256;
      int kr = idx >> 5, c4 = idx & 31;
      *reinterpret_cast<float4*>(&wsb[kr*128 + c4*4]) = ld4(&Bm[(size_t)(k0+kr)*N + n0 + c4*4]);
    }
    __syncthreads();
    #pragma unroll
    for (int kk=0;kk<32;kk++) {
      float4 bv = *reinterpret_cast<const float4*>(&wsb[kk*128 + tc*4]);
      #pragma unroll
      for (int i=0;i<8;i++) {
        float a = xs[(tr*8+i)*32 + kk];
        acc[i].x += a*bv.x; acc[i].y += a*bv.y; acc[i].z += a*bv.z; acc[i].w += a*bv.w;
      }
    }
    __syncthreads();
  }
  #pragma unroll
  for (int i=0;i<8;i++) {
    int row = tr*8+i;
    *reinterpret_cast<float4*>(&Cp[((size_t)kc*64 + row)*N + n0 + tc*4]) = acc[i];
  }
}

// ---------------- reduce q partials + split nope/pe + rope ----------------
__global__ __launch_bounds__(256) void reduce_rope(const float* __restrict__ qp,
    const int* __restrict__ positions, float* __restrict__ qn, float* __restrict__ qfull) {
  __shared__ float pe[H_*ROPE_];
  const int b = blockIdx.x, t = threadIdx.x;
  for (int n = t*4; n < NQ_; n += 1024) {
    float4 s = make_float4(0.f,0.f,0.f,0.f);
    for (int c=0;c<KCH_;c++) {
      float4 v = ld4(&qp[((size_t)c*64 + b)*NQ_ + n]);
      s.x+=v.x; s.y+=v.y; s.z+=v.z; s.w+=v.w;
    }
    float vs[4] = {s.x,s.y,s.z,s.w};
    #pragma unroll
    for (int e=0;e<4;e++) {
      int nn = n+e; int h = nn/DQ_; int d = nn - h*DQ_;
      if (d < NOPE_) qn[((size_t)b*H_ + h)*NOPE_ + d] = vs[e];
      else pe[h*ROPE_ + (d-NOPE_)] = vs[e];
    }
  }
  __syncthreads();
  const float pos = (float)positions[b];
  const float SC = 0.0721687836487032f; // 1/sqrt(192)
  for (int it = t; it < H_*32; it += 256) {
    int h = it >> 5, i = it & 31;
    float invf = (float)exp(-(double)i * 0.28782313662425574); // 10000^(-i/32)
    float fr = pos * invf;
    float cs = cosf(fr), sn = sinf(fr);
    float q1 = pe[h*ROPE_ + i], q2 = pe[h*ROPE_ + 32 + i];
    qfull[((size_t)b*H_ + h)*DKV_ + R_ + i]      = (q1*cs - q2*sn)*SC;
    qfull[((size_t)b*H_ + h)*DKV_ + R_ + 32 + i] = (q2*cs + q1*sn)*SC;
  }
}

// ---------------- ql = q_nope @ W_K[h]^T, scaled, written into qfull[:, :, 0:512] ----------------
__global__ __launch_bounds__(256) void ql_gemm(const float* __restrict__ qn,
    const float* __restrict__ WK, const float* __restrict__ WKs, float* __restrict__ qfull) {
  // grid (H_, R_/64)
  __shared__ float As[64*132];
  __shared__ float Bs[64*132];
  const int h = blockIdx.x, rt = blockIdx.y, t = threadIdx.x;
  #pragma unroll
  for (int l=0;l<8;l++) {
    int idx = t + l*256;
    int row = idx >> 5, c4 = idx & 31;
    *reinterpret_cast<float4*>(&As[row*132 + c4*4]) = ld4(&qn[((size_t)row*H_ + h)*NOPE_ + c4*4]);
    *reinterpret_cast<float4*>(&Bs[row*132 + c4*4]) = ld4(&WK[((size_t)h*R_ + rt*64 + row)*NOPE_ + c4*4]);
  }
  __syncthreads();
  const int tb = t & 15, tr2 = t >> 4;
  float acc[4][4] = {};
  for (int k=0;k<NOPE_;k++) {
    float a[4], bb[4];
    #pragma unroll
    for (int i=0;i<4;i++) a[i] = As[(tb+16*i)*132 + k];
    #pragma unroll
    for (int j=0;j<4;j++) bb[j] = Bs[(tr2+16*j)*132 + k];
    #pragma unroll
    for (int i=0;i<4;i++)
      #pragma unroll
      for (int j=0;j<4;j++) acc[i][j] += a[i]*bb[j];
  }
  const float sc = WKs[0] * 0.0721687836487032f;
  #pragma unroll
  for (int i=0;i<4;i++)
    #pragma unroll
    for (int j=0;j<4;j++) {
      int b = tb+16*i, r = rt*64 + tr2 + 16*j;
      qfull[((size_t)b*H_ + h)*DKV_ + r] = acc[i][j]*sc;
    }
}

// ---------------- flash-decode attention chunk ----------------
__global__ __launch_bounds__(256, 2) void attn_chunk(const float* __restrict__ qfull,
    const float* __restrict__ kv, const int* __restrict__ topk,
    float* __restrict__ om, float* __restrict__ ol, float* __restrict__ op) {
  __shared__ float rows[8*584];   // 8 gathered kv rows, padded
  __shared__ float P[H_*9];       // probs for current 8 rows
  __shared__ float fl[H_];        // per-head rescale factor
  const int kc = blockIdx.x, b = blockIdx.y, t = threadIdx.x;
  const int hs = t >> 3, p = t & 7;   // score mapping: head, q-slice
  const int rs = t >> 3, a = t & 7;   // o mapping: r-slice, head-base
  float4 q4[18];
  {
    const float* qb = &qfull[((size_t)b*H_ + hs)*DKV_ + p*72];
    #pragma unroll
    for (int i=0;i<18;i++) q4[i] = ld4(qb + i*4);
  }
  float m_run = -INFINITY, l_run = 0.f;
  float4 oa[4][4];
  #pragma unroll
  for (int j=0;j<4;j++)
    #pragma unroll
    for (int q=0;q<4;q++) oa[j][q] = make_float4(0.f,0.f,0.f,0.f);
  const int kbase = b*TOPK_ + kc*CHUNK_;
  for (int g=0; g<CHUNK_/8; g++) {
    for (int idx = t; idx < 8*144; idx += 256) {
      int row = idx/144, c = idx - row*144;
      int ki = topk[kbase + g*8 + row];
      *reinterpret_cast<float4*>(&rows[row*584 + c*4]) = ld4(&kv[((size_t)b*S_ + ki)*DKV_ + c*4]);
    }
    __syncthreads();
    // scores: 8 rows x 32 heads; q in regs, rows from LDS
    float pv[8];
    float tmax = -INFINITY;
    #pragma unroll
    for (int kk=0;kk<8;kk++) {
      float4 acc = make_float4(0.f,0.f,0.f,0.f);
      const float* rb = &rows[kk*584 + p*72];
      #pragma unroll
      for (int i=0;i<18;i++) {
        float4 r = *reinterpret_cast<const float4*>(rb + i*4);
        acc.x += r.x*q4[i].x; acc.y += r.y*q4[i].y; acc.z += r.z*q4[i].z; acc.w += r.w*q4[i].w;
      }
      float s = (acc.x+acc.y)+(acc.z+acc.w);
      s += __shfl_xor(s, 1);
      s += __shfl_xor(s, 2);
      s += __shfl_xor(s, 4);
      pv[kk] = s;
      tmax = fmaxf(tmax, s);
    }
    float m_new = fmaxf(m_run, tmax);
    float f = __expf(m_run - m_new);
    float psum = 0.f;
    #pragma unroll
    for (int kk=0;kk<8;kk++) { pv[kk] = __expf(pv[kk]-m_new); psum += pv[kk]; }
    l_run = l_run*f + psum;
    m_run = m_new;
    P[hs*9 + p] = pv[p];
    if (p==0) fl[hs] = f;
    __syncthreads();
    // o accumulate: thread owns heads {a+8j}, r in [rs*16, rs*16+16)
    float fj[4];
    #pragma unroll
    for (int j=0;j<4;j++) fj[j] = fl[a+8*j];
    #pragma unroll
    for (int j=0;j<4;j++)
      #pragma unroll
      for (int q=0;q<4;q++) { oa[j][q].x*=fj[j]; oa[j][q].y*=fj[j]; oa[j][q].z*=fj[j]; oa[j][q].w*=fj[j]; }
    #pragma unroll
    for (int kk=0;kk<8;kk++) {
      float p4[4];
      #pragma unroll
      for (int j=0;j<4;j++) p4[j] = P[(a+8*j)*9 + kk];
      #pragma unroll
      for (int c=0;c<4;c++) {
        int q = (c+rs)&3;   // bank-spread rotation
        float4 v = *reinterpret_cast<const float4*>(&rows[kk*584 + rs*16 + q*4]);
        #pragma unroll
        for (int j=0;j<4;j++) {
          oa[j][q].x += p4[j]*v.x; oa[j][q].y += p4[j]*v.y; oa[j][q].z += p4[j]*v.z; oa[j][q].w += p4[j]*v.w;
        }
      }
    }
    __syncthreads();
  }
  #pragma unroll
  for (int j=0;j<4;j++)
    #pragma unroll
    for (int q=0;q<4;q++)
      *reinterpret_cast<float4*>(&op[(((size_t)(b*ACH_+kc))*H_ + a+8*j)*R_ + rs*16 + q*4]) = oa[j][q];
  if (p==0) { om[(b*ACH_+kc)*H_ + hs] = m_run; ol[(b*ACH_+kc)*H_ + hs] = l_run; }
}

// ---------------- merge chunk partials ----------------
__global__ __launch_bounds__(128) void attn_merge(const float* __restrict__ om,
    const float* __restrict__ ol, const float* __restrict__ op, float* __restrict__ obuf) {
  const int bh = blockIdx.x;
  const int b = bh >> 5, h = bh & 31;
  const int t = threadIdx.x;
  float mv[8], lv[8], w[8];
  float M = -INFINITY;
  #pragma unroll
  for (int c=0;c<8;c++) { mv[c] = om[(b*ACH_+c)*H_ + h]; lv[c] = ol[(b*ACH_+c)*H_+h]; M = fmaxf(M, mv[c]); }
  float L = 0.f;
  #pragma unroll
  for (int c=0;c<8;c++) { w[c] = __expf(mv[c]-M); L += lv[c]*w[c]; }
  float inv = 1.0f / L;
  float4 s = make_float4(0.f,0.f,0.f,0.f);
  #pragma unroll
  for (int c=0;c<8;c++) {
    float4 v = ld4(&op[(((size_t)(b*ACH_+c))*H_ + h)*R_ + t*4]);
    s.x += v.x*w[c]; s.y += v.y*w[c]; s.z += v.z*w[c]; s.w += v.w*w[c];
  }
  s.x*=inv; s.y*=inv; s.z*=inv; s.w*=inv;
  *reinterpret_cast<float4*>(&obuf[((size_t)b*H_+h)*R_ + t*4]) = s;
}

// ---------------- out = o @ W_V[h]^T * scale ----------------
__global__ __launch_bounds__(256) void vproj(const float* __restrict__ obuf,
    const float* __restrict__ WV, const float* __restrict__ WVs, float* __restrict__ mid) {
  // grid (H_, 2)
  __shared__ float As[64*68];
  __shared__ float Bs[64*68];
  const int h = blockIdx.x, vt = blockIdx.y, t = threadIdx.x;
  const int tb = t & 15, tr2 = t >> 4;
  float acc[4][4] = {};
  for (int k0=0;k0<R_;k0+=64) {
    #pragma unroll
    for (int l=0;l<4;l++) {
      int idx = t + l*256;
      int row = idx >> 4, c4 = idx & 15;
      *reinterpret_cast<float4*>(&As[row*68 + c4*4]) = ld4(&obuf[((size_t)row*H_+h)*R_ + k0 + c4*4]);
      *reinterpret_cast<float4*>(&Bs[row*68 + c4*4]) = ld4(&WV[((size_t)h*V_ + vt*64 + row)*R_ + k0 + c4*4]);
    }
    __syncthreads();
    #pragma unroll
    for (int k=0;k<64;k++) {
      float a[4], bb[4];
      #pragma unroll
      for (int i=0;i<4;i++) a[i] = As[(tb+16*i)*68 + k];
      #pragma unroll
      for (int j=0;j<4;j++) bb[j] = Bs[(tr2+16*j)*68 + k];
      #pragma unroll
      for (int i=0;i<4;i++)
        #pragma unroll
        for (int j=0;j<4;j++) acc[i][j] += a[i]*bb[j];
    }
    __syncthreads();
  }
  const float sc = WVs[0];
  #pragma unroll
  for (int i=0;i<4;i++)
    #pragma unroll
    for (int j=0;j<4;j++)
      mid[(size_t)(tb+16*i)*HID_ + h*V_ + vt*64 + tr2 + 16*j] = acc[i][j]*sc;
}

// ---------------- final reduce of Wo partials ----------------
__global__ __launch_bounds__(256) void reduce_out(const float* __restrict__ op2, float* __restrict__ out) {
  int idx = blockIdx.x*256 + threadIdx.x; // float4 index
  float4 s = make_float4(0.f,0.f,0.f,0.f);
  #pragma unroll
  for (int c=0;c<KCH_;c++) {
    float4 v = ld4(&op2[(size_t)c*B_*HID_ + (size_t)idx*4]);
    s.x+=v.x; s.y+=v.y; s.z+=v.z; s.w+=v.w;
  }
  *reinterpret_cast<float4*>(&out[(size_t)idx*4]) = s;
}

extern "C" void kernel_launch(void* const* d_in, const int* in_sizes, int n_in,
                              void* d_out, int out_size, void* d_ws, size_t ws_size,
                              hipStream_t stream) {
  (void)in_sizes; (void)n_in; (void)out_size; (void)ws_size;
  const float* x   = (const float*)d_in[0];
  const float* Wq  = (const float*)d_in[1];
  const float* WK  = (const float*)d_in[2];
  const float* WKs = (const float*)d_in[3];
  const float* WV  = (const float*)d_in[4];
  const float* WVs = (const float*)d_in[5];
  const float* Wo  = (const float*)d_in[6];
  const float* kv  = (const float*)d_in[7];
  const int* topk  = (const int*)d_in[8];
  const int* pos   = (const int*)d_in[9];
  float* ws = (float*)d_ws;
  float* qp    = ws;                                   // 8*64*6144    = 3,145,728
  float* qn    = qp    + (size_t)8*64*6144;            // 64*32*128    =   262,144
  float* qfull = qn    + (size_t)64*32*128;            // 64*32*576    = 1,179,648
  float* om    = qfull + (size_t)64*32*576;            // 64*8*32
  float* ol    = om    + (size_t)64*8*32;              // 64*8*32
  float* op    = ol    + (size_t)64*8*32;              // 64*8*32*512  = 8,388,608
  float* obuf  = op    + (size_t)64*8*32*512;          // 64*32*512    = 1,048,576
  float* mid   = obuf  + (size_t)64*32*512;            // 64*4096      =   262,144
  float* op2   = mid   + (size_t)64*4096;              // 8*64*4096    = 2,097,152
  float* outf  = (float*)d_out;

  gemm64_partial<<<dim3(48,8),256,0,stream>>>(x, Wq, qp, NQ_, HID_);
  reduce_rope<<<64,256,0,stream>>>(qp, pos, qn, qfull);
  ql_gemm<<<dim3(32,8),256,0,stream>>>(qn, WK, WKs, qfull);
  attn_chunk<<<dim3(8,64),256,0,stream>>>(qfull, kv, topk, om, ol, op);
  attn_merge<<<2048,128,0,stream>>>(om, ol, op, obuf);
  vproj<<<dim3(32,2),256,0,stream>>>(obuf, WV, WVs, mid);
  gemm64_partial<<<dim3(32,8),256,0,stream>>>(mid, Wo, op2, HID_, HID_);
  reduce_out<<<256,256,0,stream>>>(op2, outf);
}

// Round 2
// 2891.503 us; speedup vs baseline: 1.7502x; 1.7502x over previous
//
#include <hip/hip_runtime.h>
#include <hip/hip_bf16.h>
#include <math.h>

#define H_ 32
#define R_ 512
#define NOPE_ 128
#define ROPE_ 64
#define V_ 128
#define HID_ 4096
#define B_ 64
#define S_ 4096
#define TOPK_ 2048
#define DQ_ 192      // NOPE+ROPE
#define NQ_ 6144     // H*DQ
#define DKV_ 576     // R+ROPE
#define KCH_ 8       // K-chunks for partial skinny GEMMs
#define ACH_ 8       // attention k-chunks
#define CHUNK_ 256   // TOPK/ACH
#define ROWS_ 16     // gathered rows per inner iteration
#define RSTRIDE_ 584 // padded row stride in LDS floats

__device__ __forceinline__ float4 ld4(const float* p) { return *reinterpret_cast<const float4*>(p); }

// ---------------- skinny partial GEMM: C_partial[kc] = A(64 x Kchunk) @ B ----------------
__global__ __launch_bounds__(256) void gemm64_partial(const float* __restrict__ A,
    const float* __restrict__ Bm, float* __restrict__ Cp, int N, int K) {
  // grid: (N/128, KCH_)
  __shared__ float xs[64*32];
  __shared__ float wsb[32*128];
  const int t = threadIdx.x;
  const int nt = blockIdx.x, kc = blockIdx.y;
  const int n0 = nt*128;
  const int kchunk = K / KCH_;
  const int kbeg = kc*kchunk;
  const int tr = t >> 5, tc = t & 31;
  float4 acc[8];
  #pragma unroll
  for (int i=0;i<8;i++) acc[i] = make_float4(0.f,0.f,0.f,0.f);
  for (int k0 = kbeg; k0 < kbeg + kchunk; k0 += 32) {
    #pragma unroll
    for (int l=0;l<2;l++) {
      int idx = t + l*256;
      int row = idx >> 3, c4 = idx & 7;
      *reinterpret_cast<float4*>(&xs[row*32 + c4*4]) = ld4(&A[(size_t)row*K + k0 + c4*4]);
    }
    #pragma unroll
    for (int l=0;l<4;l++) {
      int idx = t + l*256;
      int kr = idx >> 5, c4 = idx & 31;
      *reinterpret_cast<float4*>(&wsb[kr*128 + c4*4]) = ld4(&Bm[(size_t)(k0+kr)*N + n0 + c4*4]);
    }
    __syncthreads();
    #pragma unroll
    for (int kk=0;kk<32;kk++) {
      float4 bv = *reinterpret_cast<const float4*>(&wsb[kk*128 + tc*4]);
      #pragma unroll
      for (int i=0;i<8;i++) {
        float a = xs[(tr*8+i)*32 + kk];
        acc[i].x += a*bv.x; acc[i].y += a*bv.y; acc[i].z += a*bv.z; acc[i].w += a*bv.w;
      }
    }
    __syncthreads();
  }
  #pragma unroll
  for (int i=0;i<8;i++) {
    int row = tr*8+i;
    *reinterpret_cast<float4*>(&Cp[((size_t)kc*64 + row)*N + n0 + tc*4]) = acc[i];
  }
}

// ---------------- reduce q partials + split nope/pe + rope ----------------
__global__ __launch_bounds__(256) void reduce_rope(const float* __restrict__ qp,
    const int* __restrict__ positions, float* __restrict__ qn, float* __restrict__ qfull) {
  __shared__ float pe[H_*ROPE_];
  const int b = blockIdx.x, t = threadIdx.x;
  for (int n = t*4; n < NQ_; n += 1024) {
    float4 s = make_float4(0.f,0.f,0.f,0.f);
    for (int c=0;c<KCH_;c++) {
      float4 v = ld4(&qp[((size_t)c*64 + b)*NQ_ + n]);
      s.x+=v.x; s.y+=v.y; s.z+=v.z; s.w+=v.w;
    }
    float vs[4] = {s.x,s.y,s.z,s.w};
    #pragma unroll
    for (int e=0;e<4;e++) {
      int nn = n+e; int h = nn/DQ_; int d = nn - h*DQ_;
      if (d < NOPE_) qn[((size_t)b*H_ + h)*NOPE_ + d] = vs[e];
      else pe[h*ROPE_ + (d-NOPE_)] = vs[e];
    }
  }
  __syncthreads();
  const float pos = (float)positions[b];
  const float SC = 0.0721687836487032f; // 1/sqrt(192)
  for (int it = t; it < H_*32; it += 256) {
    int h = it >> 5, i = it & 31;
    float invf = (float)exp(-(double)i * 0.28782313662425574); // 10000^(-i/32)
    float fr = pos * invf;
    float cs = cosf(fr), sn = sinf(fr);
    float q1 = pe[h*ROPE_ + i], q2 = pe[h*ROPE_ + 32 + i];
    qfull[((size_t)b*H_ + h)*DKV_ + R_ + i]      = (q1*cs - q2*sn)*SC;
    qfull[((size_t)b*H_ + h)*DKV_ + R_ + 32 + i] = (q2*cs + q1*sn)*SC;
  }
}

// ---------------- ql = q_nope @ W_K[h]^T, scaled, written into qfull[:, :, 0:512] ----------------
__global__ __launch_bounds__(256) void ql_gemm(const float* __restrict__ qn,
    const float* __restrict__ WK, const float* __restrict__ WKs, float* __restrict__ qfull) {
  // grid (H_, R_/64)
  __shared__ float As[64*132];
  __shared__ float Bs[64*132];
  const int h = blockIdx.x, rt = blockIdx.y, t = threadIdx.x;
  #pragma unroll
  for (int l=0;l<8;l++) {
    int idx = t + l*256;
    int row = idx >> 5, c4 = idx & 31;
    *reinterpret_cast<float4*>(&As[row*132 + c4*4]) = ld4(&qn[((size_t)row*H_ + h)*NOPE_ + c4*4]);
    *reinterpret_cast<float4*>(&Bs[row*132 + c4*4]) = ld4(&WK[((size_t)h*R_ + rt*64 + row)*NOPE_ + c4*4]);
  }
  __syncthreads();
  const int tb = t & 15, tr2 = t >> 4;
  float acc[4][4] = {};
  for (int k=0;k<NOPE_;k++) {
    float a[4], bb[4];
    #pragma unroll
    for (int i=0;i<4;i++) a[i] = As[(tb+16*i)*132 + k];
    #pragma unroll
    for (int j=0;j<4;j++) bb[j] = Bs[(tr2+16*j)*132 + k];
    #pragma unroll
    for (int i=0;i<4;i++)
      #pragma unroll
      for (int j=0;j<4;j++) acc[i][j] += a[i]*bb[j];
  }
  const float sc = WKs[0] * 0.0721687836487032f;
  #pragma unroll
  for (int i=0;i<4;i++)
    #pragma unroll
    for (int j=0;j<4;j++) {
      int b = tb+16*i, r = rt*64 + tr2 + 16*j;
      qfull[((size_t)b*H_ + h)*DKV_ + r] = acc[i][j]*sc;
    }
}

// ---------------- flash-decode attention chunk (no VGPR cap -> no spill) ----------------
__global__ __launch_bounds__(256) void attn_chunk(const float* __restrict__ qfull,
    const float* __restrict__ kv, const int* __restrict__ topk,
    float* __restrict__ om, float* __restrict__ ol, float* __restrict__ op) {
  __shared__ float rows[ROWS_*RSTRIDE_];   // 16 gathered kv rows, padded
  __shared__ float P[H_*(ROWS_+1)];        // probs for current 16 rows
  __shared__ float fl[H_];                 // per-head rescale factor
  const int kc = blockIdx.x, b = blockIdx.y, t = threadIdx.x;
  const int hs = t >> 3, p = t & 7;   // score mapping: head, q-slice
  const int rs = t >> 3, a = t & 7;   // o mapping: r-slice, head-base
  float4 q4[18];
  {
    const float* qb = &qfull[((size_t)b*H_ + hs)*DKV_ + p*72];
    #pragma unroll
    for (int i=0;i<18;i++) q4[i] = ld4(qb + i*4);
  }
  float m_run = -INFINITY, l_run = 0.f;
  float4 oa[4][4];
  #pragma unroll
  for (int j=0;j<4;j++)
    #pragma unroll
    for (int q=0;q<4;q++) oa[j][q] = make_float4(0.f,0.f,0.f,0.f);
  const int kbase = b*TOPK_ + kc*CHUNK_;
  for (int g=0; g<CHUNK_/ROWS_; g++) {
    #pragma unroll
    for (int l=0;l<9;l++) {
      int idx = t + l*256;                 // 16*144 = 2304 = 9*256 exactly
      int row = idx/144, c = idx - row*144;
      int ki = topk[kbase + g*ROWS_ + row];
      *reinterpret_cast<float4*>(&rows[row*RSTRIDE_ + c*4]) = ld4(&kv[((size_t)b*S_ + ki)*DKV_ + c*4]);
    }
    __syncthreads();
    // scores: 16 rows x 32 heads; q in regs, rows from LDS
    float pv[ROWS_];
    float tmax = -INFINITY;
    #pragma unroll
    for (int kk=0;kk<ROWS_;kk++) {
      float4 acc = make_float4(0.f,0.f,0.f,0.f);
      const float* rb = &rows[kk*RSTRIDE_ + p*72];
      #pragma unroll
      for (int i=0;i<18;i++) {
        float4 r = *reinterpret_cast<const float4*>(rb + i*4);
        acc.x += r.x*q4[i].x; acc.y += r.y*q4[i].y; acc.z += r.z*q4[i].z; acc.w += r.w*q4[i].w;
      }
      float s = (acc.x+acc.y)+(acc.z+acc.w);
      s += __shfl_xor(s, 1);
      s += __shfl_xor(s, 2);
      s += __shfl_xor(s, 4);
      pv[kk] = s;
      tmax = fmaxf(tmax, s);
    }
    float m_new = fmaxf(m_run, tmax);
    float f = __expf(m_run - m_new);
    float psum = 0.f;
    #pragma unroll
    for (int kk=0;kk<ROWS_;kk++) { pv[kk] = __expf(pv[kk]-m_new); psum += pv[kk]; }
    l_run = l_run*f + psum;
    m_run = m_new;
    P[hs*(ROWS_+1) + p] = pv[p];
    P[hs*(ROWS_+1) + p + 8] = pv[p+8];
    if (p==0) fl[hs] = f;
    __syncthreads();
    // o accumulate: thread owns heads {a+8j}, r in [rs*16, rs*16+16)
    float fj[4];
    #pragma unroll
    for (int j=0;j<4;j++) fj[j] = fl[a+8*j];
    #pragma unroll
    for (int j=0;j<4;j++)
      #pragma unroll
      for (int q=0;q<4;q++) { oa[j][q].x*=fj[j]; oa[j][q].y*=fj[j]; oa[j][q].z*=fj[j]; oa[j][q].w*=fj[j]; }
    #pragma unroll
    for (int kk=0;kk<ROWS_;kk++) {
      float p4[4];
      #pragma unroll
      for (int j=0;j<4;j++) p4[j] = P[(a+8*j)*(ROWS_+1) + kk];
      #pragma unroll
      for (int c=0;c<4;c++) {
        int q = (c+rs)&3;   // bank-spread rotation
        float4 v = *reinterpret_cast<const float4*>(&rows[kk*RSTRIDE_ + rs*16 + q*4]);
        #pragma unroll
        for (int j=0;j<4;j++) {
          oa[j][q].x += p4[j]*v.x; oa[j][q].y += p4[j]*v.y; oa[j][q].z += p4[j]*v.z; oa[j][q].w += p4[j]*v.w;
        }
      }
    }
    __syncthreads();
  }
  #pragma unroll
  for (int j=0;j<4;j++)
    #pragma unroll
    for (int q=0;q<4;q++)
      *reinterpret_cast<float4*>(&op[(((size_t)(b*ACH_+kc))*H_ + a+8*j)*R_ + rs*16 + q*4]) = oa[j][q];
  if (p==0) { om[(b*ACH_+kc)*H_ + hs] = m_run; ol[(b*ACH_+kc)*H_ + hs] = l_run; }
}

// ---------------- merge chunk partials ----------------
__global__ __launch_bounds__(128) void attn_merge(const float* __restrict__ om,
    const float* __restrict__ ol, const float* __restrict__ op, float* __restrict__ obuf) {
  const int bh = blockIdx.x;
  const int b = bh >> 5, h = bh & 31;
  const int t = threadIdx.x;
  float mv[8], lv[8], w[8];
  float M = -INFINITY;
  #pragma unroll
  for (int c=0;c<8;c++) { mv[c] = om[(b*ACH_+c)*H_ + h]; lv[c] = ol[(b*ACH_+c)*H_+h]; M = fmaxf(M, mv[c]); }
  float L = 0.f;
  #pragma unroll
  for (int c=0;c<8;c++) { w[c] = __expf(mv[c]-M); L += lv[c]*w[c]; }
  float inv = 1.0f / L;
  float4 s = make_float4(0.f,0.f,0.f,0.f);
  #pragma unroll
  for (int c=0;c<8;c++) {
    float4 v = ld4(&op[(((size_t)(b*ACH_+c))*H_ + h)*R_ + t*4]);
    s.x += v.x*w[c]; s.y += v.y*w[c]; s.z += v.z*w[c]; s.w += v.w*w[c];
  }
  s.x*=inv; s.y*=inv; s.z*=inv; s.w*=inv;
  *reinterpret_cast<float4*>(&obuf[((size_t)b*H_+h)*R_ + t*4]) = s;
}

// ---------------- out = o @ W_V[h]^T * scale ----------------
__global__ __launch_bounds__(256) void vproj(const float* __restrict__ obuf,
    const float* __restrict__ WV, const float* __restrict__ WVs, float* __restrict__ mid) {
  // grid (H_, 2)
  __shared__ float As[64*68];
  __shared__ float Bs[64*68];
  const int h = blockIdx.x, vt = blockIdx.y, t = threadIdx.x;
  const int tb = t & 15, tr2 = t >> 4;
  float acc[4][4] = {};
  for (int k0=0;k0<R_;k0+=64) {
    #pragma unroll
    for (int l=0;l<4;l++) {
      int idx = t + l*256;
      int row = idx >> 4, c4 = idx & 15;
      *reinterpret_cast<float4*>(&As[row*68 + c4*4]) = ld4(&obuf[((size_t)row*H_+h)*R_ + k0 + c4*4]);
      *reinterpret_cast<float4*>(&Bs[row*68 + c4*4]) = ld4(&WV[((size_t)h*V_ + vt*64 + row)*R_ + k0 + c4*4]);
    }
    __syncthreads();
    #pragma unroll
    for (int k=0;k<64;k++) {
      float a[4], bb[4];
      #pragma unroll
      for (int i=0;i<4;i++) a[i] = As[(tb+16*i)*68 + k];
      #pragma unroll
      for (int j=0;j<4;j++) bb[j] = Bs[(tr2+16*j)*68 + k];
      #pragma unroll
      for (int i=0;i<4;i++)
        #pragma unroll
        for (int j=0;j<4;j++) acc[i][j] += a[i]*bb[j];
    }
    __syncthreads();
  }
  const float sc = WVs[0];
  #pragma unroll
  for (int i=0;i<4;i++)
    #pragma unroll
    for (int j=0;j<4;j++)
      mid[(size_t)(tb+16*i)*HID_ + h*V_ + vt*64 + tr2 + 16*j] = acc[i][j]*sc;
}

// ---------------- final reduce of Wo partials ----------------
__global__ __launch_bounds__(256) void reduce_out(const float* __restrict__ op2, float* __restrict__ out) {
  int idx = blockIdx.x*256 + threadIdx.x; // float4 index
  float4 s = make_float4(0.f,0.f,0.f,0.f);
  #pragma unroll
  for (int c=0;c<KCH_;c++) {
    float4 v = ld4(&op2[(size_t)c*B_*HID_ + (size_t)idx*4]);
    s.x+=v.x; s.y+=v.y; s.z+=v.z; s.w+=v.w;
  }
  *reinterpret_cast<float4*>(&out[(size_t)idx*4]) = s;
}

extern "C" void kernel_launch(void* const* d_in, const int* in_sizes, int n_in,
                              void* d_out, int out_size, void* d_ws, size_t ws_size,
                              hipStream_t stream) {
  (void)in_sizes; (void)n_in; (void)out_size; (void)ws_size;
  const float* x   = (const float*)d_in[0];
  const float* Wq  = (const float*)d_in[1];
  const float* WK  = (const float*)d_in[2];
  const float* WKs = (const float*)d_in[3];
  const float* WV  = (const float*)d_in[4];
  const float* WVs = (const float*)d_in[5];
  const float* Wo  = (const float*)d_in[6];
  const float* kv  = (const float*)d_in[7];
  const int* topk  = (const int*)d_in[8];
  const int* pos   = (const int*)d_in[9];
  float* ws = (float*)d_ws;
  float* qp    = ws;                                   // 8*64*6144    = 3,145,728
  float* qn    = qp    + (size_t)8*64*6144;            // 64*32*128    =   262,144
  float* qfull = qn    + (size_t)64*32*128;            // 64*32*576    = 1,179,648
  float* om    = qfull + (size_t)64*32*576;            // 64*8*32
  float* ol    = om    + (size_t)64*8*32;              // 64*8*32
  float* op    = ol    + (size_t)64*8*32;              // 64*8*32*512  = 8,388,608
  float* obuf  = op    + (size_t)64*8*32*512;          // 64*32*512    = 1,048,576
  float* mid   = obuf  + (size_t)64*32*512;            // 64*4096      =   262,144
  float* op2   = mid   + (size_t)64*4096;              // 8*64*4096    = 2,097,152
  float* outf  = (float*)d_out;

  gemm64_partial<<<dim3(48,8),256,0,stream>>>(x, Wq, qp, NQ_, HID_);
  reduce_rope<<<64,256,0,stream>>>(qp, pos, qn, qfull);
  ql_gemm<<<dim3(32,8),256,0,stream>>>(qn, WK, WKs, qfull);
  attn_chunk<<<dim3(8,64),256,0,stream>>>(qfull, kv, topk, om, ol, op);
  attn_merge<<<2048,128,0,stream>>>(om, ol, op, obuf);
  vproj<<<dim3(32,2),256,0,stream>>>(obuf, WV, WVs, mid);
  gemm64_partial<<<dim3(32,8),256,0,stream>>>(mid, Wo, op2, HID_, HID_);
  reduce_out<<<256,256,0,stream>>>(op2, outf);
}

// Round 3
// 501.317 us; speedup vs baseline: 10.0948x; 5.7678x over previous
//
#include <hip/hip_runtime.h>
#include <hip/hip_bf16.h>
#include <math.h>

#define H_ 32
#define R_ 512
#define NOPE_ 128
#define ROPE_ 64
#define V_ 128
#define HID_ 4096
#define B_ 64
#define S_ 4096
#define TOPK_ 2048
#define DQ_ 192      // NOPE+ROPE
#define NQ_ 6144     // H*DQ
#define DKV_ 576     // R+ROPE
#define KCH_ 8       // K-chunks for partial skinny GEMMs
#define ACH_ 8       // attention k-chunks
#define CHUNK_ 256   // TOPK/ACH
#define ROWS_ 16     // gathered rows per inner iteration
#define RSTRIDE_ 584 // padded row stride in LDS floats

__device__ __forceinline__ float4 ld4(const float* p) { return *reinterpret_cast<const float4*>(p); }

// ---------------- skinny partial GEMM: C_partial[kc] = A(64 x Kchunk) @ B ----------------
__global__ __launch_bounds__(256) void gemm64_partial(const float* __restrict__ A,
    const float* __restrict__ Bm, float* __restrict__ Cp, int N, int K) {
  // grid: (N/128, KCH_)
  __shared__ float xs[64*32];
  __shared__ float wsb[32*128];
  const int t = threadIdx.x;
  const int nt = blockIdx.x, kc = blockIdx.y;
  const int n0 = nt*128;
  const int kchunk = K / KCH_;
  const int kbeg = kc*kchunk;
  const int tr = t >> 5, tc = t & 31;
  float4 acc[8];
  #pragma unroll
  for (int i=0;i<8;i++) acc[i] = make_float4(0.f,0.f,0.f,0.f);
  for (int k0 = kbeg; k0 < kbeg + kchunk; k0 += 32) {
    #pragma unroll
    for (int l=0;l<2;l++) {
      int idx = t + l*256;
      int row = idx >> 3, c4 = idx & 7;
      *reinterpret_cast<float4*>(&xs[row*32 + c4*4]) = ld4(&A[(size_t)row*K + k0 + c4*4]);
    }
    #pragma unroll
    for (int l=0;l<4;l++) {
      int idx = t + l*256;
      int kr = idx >> 5, c4 = idx & 31;
      *reinterpret_cast<float4*>(&wsb[kr*128 + c4*4]) = ld4(&Bm[(size_t)(k0+kr)*N + n0 + c4*4]);
    }
    __syncthreads();
    #pragma unroll
    for (int kk=0;kk<32;kk++) {
      float4 bv = *reinterpret_cast<const float4*>(&wsb[kk*128 + tc*4]);
      #pragma unroll
      for (int i=0;i<8;i++) {
        float a = xs[(tr*8+i)*32 + kk];
        acc[i].x += a*bv.x; acc[i].y += a*bv.y; acc[i].z += a*bv.z; acc[i].w += a*bv.w;
      }
    }
    __syncthreads();
  }
  #pragma unroll
  for (int i=0;i<8;i++) {
    int row = tr*8+i;
    *reinterpret_cast<float4*>(&Cp[((size_t)kc*64 + row)*N + n0 + tc*4]) = acc[i];
  }
}

// ---------------- reduce q partials + split nope/pe + rope ----------------
__global__ __launch_bounds__(256) void reduce_rope(const float* __restrict__ qp,
    const int* __restrict__ positions, float* __restrict__ qn, float* __restrict__ qfull) {
  __shared__ float pe[H_*ROPE_];
  const int b = blockIdx.x, t = threadIdx.x;
  for (int n = t*4; n < NQ_; n += 1024) {
    float4 s = make_float4(0.f,0.f,0.f,0.f);
    for (int c=0;c<KCH_;c++) {
      float4 v = ld4(&qp[((size_t)c*64 + b)*NQ_ + n]);
      s.x+=v.x; s.y+=v.y; s.z+=v.z; s.w+=v.w;
    }
    float vs[4] = {s.x,s.y,s.z,s.w};
    #pragma unroll
    for (int e=0;e<4;e++) {
      int nn = n+e; int h = nn/DQ_; int d = nn - h*DQ_;
      if (d < NOPE_) qn[((size_t)b*H_ + h)*NOPE_ + d] = vs[e];
      else pe[h*ROPE_ + (d-NOPE_)] = vs[e];
    }
  }
  __syncthreads();
  const float pos = (float)positions[b];
  const float SC = 0.0721687836487032f; // 1/sqrt(192)
  for (int it = t; it < H_*32; it += 256) {
    int h = it >> 5, i = it & 31;
    float invf = (float)exp(-(double)i * 0.28782313662425574); // 10000^(-i/32)
    float fr = pos * invf;
    float cs = cosf(fr), sn = sinf(fr);
    float q1 = pe[h*ROPE_ + i], q2 = pe[h*ROPE_ + 32 + i];
    qfull[((size_t)b*H_ + h)*DKV_ + R_ + i]      = (q1*cs - q2*sn)*SC;
    qfull[((size_t)b*H_ + h)*DKV_ + R_ + 32 + i] = (q2*cs + q1*sn)*SC;
  }
}

// ---------------- ql = q_nope @ W_K[h]^T, scaled, written into qfull[:, :, 0:512] ----------------
__global__ __launch_bounds__(256) void ql_gemm(const float* __restrict__ qn,
    const float* __restrict__ WK, const float* __restrict__ WKs, float* __restrict__ qfull) {
  // grid (H_, R_/64)
  __shared__ float As[64*132];
  __shared__ float Bs[64*132];
  const int h = blockIdx.x, rt = blockIdx.y, t = threadIdx.x;
  #pragma unroll
  for (int l=0;l<8;l++) {
    int idx = t + l*256;
    int row = idx >> 5, c4 = idx & 31;
    *reinterpret_cast<float4*>(&As[row*132 + c4*4]) = ld4(&qn[((size_t)row*H_ + h)*NOPE_ + c4*4]);
    *reinterpret_cast<float4*>(&Bs[row*132 + c4*4]) = ld4(&WK[((size_t)h*R_ + rt*64 + row)*NOPE_ + c4*4]);
  }
  __syncthreads();
  const int tb = t & 15, tr2 = t >> 4;
  float acc[4][4] = {};
  for (int k=0;k<NOPE_;k++) {
    float a[4], bb[4];
    #pragma unroll
    for (int i=0;i<4;i++) a[i] = As[(tb+16*i)*132 + k];
    #pragma unroll
    for (int j=0;j<4;j++) bb[j] = Bs[(tr2+16*j)*132 + k];
    #pragma unroll
    for (int i=0;i<4;i++)
      #pragma unroll
      for (int j=0;j<4;j++) acc[i][j] += a[i]*bb[j];
  }
  const float sc = WKs[0] * 0.0721687836487032f;
  #pragma unroll
  for (int i=0;i<4;i++)
    #pragma unroll
    for (int j=0;j<4;j++) {
      int b = tb+16*i, r = rt*64 + tr2 + 16*j;
      qfull[((size_t)b*H_ + h)*DKV_ + r] = acc[i][j]*sc;
    }
}

// ---------------- flash-decode attention chunk ----------------
// Register indices are ALL compile-time static (rule: runtime-indexed arrays go
// to scratch). The bank-spread rotation lives in the LDS/global ADDRESSES only:
// thread's oa[j][c] permanently owns output column qc=(c+rs)&3.
__global__ __launch_bounds__(256) void attn_chunk(const float* __restrict__ qfull,
    const float* __restrict__ kv, const int* __restrict__ topk,
    float* __restrict__ om, float* __restrict__ ol, float* __restrict__ op) {
  __shared__ float rows[ROWS_*RSTRIDE_];   // 16 gathered kv rows, padded
  __shared__ float P[H_*(ROWS_+1)];        // probs for current 16 rows
  __shared__ float fl[H_];                 // per-head rescale factor
  const int kc = blockIdx.x, b = blockIdx.y, t = threadIdx.x;
  const int hs = t >> 3, p = t & 7;   // score mapping: head, q-slice
  const int rs = t >> 3, a = t & 7;   // o mapping: r-slice, head-base
  float4 q4[18];
  {
    const float* qb = &qfull[((size_t)b*H_ + hs)*DKV_ + p*72];
    #pragma unroll
    for (int i=0;i<18;i++) q4[i] = ld4(qb + i*4);
  }
  float m_run = -INFINITY, l_run = 0.f;
  float4 oa[4][4];
  #pragma unroll
  for (int j=0;j<4;j++)
    #pragma unroll
    for (int c=0;c<4;c++) oa[j][c] = make_float4(0.f,0.f,0.f,0.f);
  const int kbase = b*TOPK_ + kc*CHUNK_;
  for (int g=0; g<CHUNK_/ROWS_; g++) {
    #pragma unroll
    for (int l=0;l<9;l++) {
      int idx = t + l*256;                 // 16*144 = 2304 = 9*256 exactly
      int row = idx/144, c = idx - row*144;
      int ki = topk[kbase + g*ROWS_ + row];
      *reinterpret_cast<float4*>(&rows[row*RSTRIDE_ + c*4]) = ld4(&kv[((size_t)b*S_ + ki)*DKV_ + c*4]);
    }
    __syncthreads();
    // scores: 16 rows x 32 heads; q in regs, rows from LDS
    float pv[ROWS_];
    float tmax = -INFINITY;
    #pragma unroll
    for (int kk=0;kk<ROWS_;kk++) {
      float4 acc = make_float4(0.f,0.f,0.f,0.f);
      const float* rb = &rows[kk*RSTRIDE_ + p*72];
      #pragma unroll
      for (int i=0;i<18;i++) {
        float4 r = *reinterpret_cast<const float4*>(rb + i*4);
        acc.x += r.x*q4[i].x; acc.y += r.y*q4[i].y; acc.z += r.z*q4[i].z; acc.w += r.w*q4[i].w;
      }
      float s = (acc.x+acc.y)+(acc.z+acc.w);
      s += __shfl_xor(s, 1);
      s += __shfl_xor(s, 2);
      s += __shfl_xor(s, 4);
      pv[kk] = s;
      tmax = fmaxf(tmax, s);
    }
    float m_new = fmaxf(m_run, tmax);
    float f = __expf(m_run - m_new);
    float psum = 0.f;
    #pragma unroll
    for (int kk=0;kk<ROWS_;kk++) { pv[kk] = __expf(pv[kk]-m_new); psum += pv[kk]; }
    l_run = l_run*f + psum;
    m_run = m_new;
    P[hs*(ROWS_+1) + p] = pv[p];
    P[hs*(ROWS_+1) + p + 8] = pv[p+8];
    if (p==0) fl[hs] = f;
    __syncthreads();
    // o accumulate: thread owns heads {a+8j}; register slot c holds column (c+rs)&3
    float fj[4];
    #pragma unroll
    for (int j=0;j<4;j++) fj[j] = fl[a+8*j];
    #pragma unroll
    for (int j=0;j<4;j++)
      #pragma unroll
      for (int c=0;c<4;c++) { oa[j][c].x*=fj[j]; oa[j][c].y*=fj[j]; oa[j][c].z*=fj[j]; oa[j][c].w*=fj[j]; }
    #pragma unroll
    for (int kk=0;kk<ROWS_;kk++) {
      float p4[4];
      #pragma unroll
      for (int j=0;j<4;j++) p4[j] = P[(a+8*j)*(ROWS_+1) + kk];
      #pragma unroll
      for (int c=0;c<4;c++) {
        const int qc = (c+rs)&3;   // runtime ADDRESS rotation, static REGISTER index
        float4 v = *reinterpret_cast<const float4*>(&rows[kk*RSTRIDE_ + rs*16 + qc*4]);
        #pragma unroll
        for (int j=0;j<4;j++) {
          oa[j][c].x += p4[j]*v.x; oa[j][c].y += p4[j]*v.y; oa[j][c].z += p4[j]*v.z; oa[j][c].w += p4[j]*v.w;
        }
      }
    }
    __syncthreads();
  }
  #pragma unroll
  for (int j=0;j<4;j++)
    #pragma unroll
    for (int c=0;c<4;c++) {
      const int qc = (c+rs)&3;
      *reinterpret_cast<float4*>(&op[(((size_t)(b*ACH_+kc))*H_ + a+8*j)*R_ + rs*16 + qc*4]) = oa[j][c];
    }
  if (p==0) { om[(b*ACH_+kc)*H_ + hs] = m_run; ol[(b*ACH_+kc)*H_ + hs] = l_run; }
}

// ---------------- merge chunk partials ----------------
__global__ __launch_bounds__(128) void attn_merge(const float* __restrict__ om,
    const float* __restrict__ ol, const float* __restrict__ op, float* __restrict__ obuf) {
  const int bh = blockIdx.x;
  const int b = bh >> 5, h = bh & 31;
  const int t = threadIdx.x;
  float mv[8], lv[8], w[8];
  float M = -INFINITY;
  #pragma unroll
  for (int c=0;c<8;c++) { mv[c] = om[(b*ACH_+c)*H_ + h]; lv[c] = ol[(b*ACH_+c)*H_+h]; M = fmaxf(M, mv[c]); }
  float L = 0.f;
  #pragma unroll
  for (int c=0;c<8;c++) { w[c] = __expf(mv[c]-M); L += lv[c]*w[c]; }
  float inv = 1.0f / L;
  float4 s = make_float4(0.f,0.f,0.f,0.f);
  #pragma unroll
  for (int c=0;c<8;c++) {
    float4 v = ld4(&op[(((size_t)(b*ACH_+c))*H_ + h)*R_ + t*4]);
    s.x += v.x*w[c]; s.y += v.y*w[c]; s.z += v.z*w[c]; s.w += v.w*w[c];
  }
  s.x*=inv; s.y*=inv; s.z*=inv; s.w*=inv;
  *reinterpret_cast<float4*>(&obuf[((size_t)b*H_+h)*R_ + t*4]) = s;
}

// ---------------- out = o @ W_V[h]^T * scale ----------------
__global__ __launch_bounds__(256) void vproj(const float* __restrict__ obuf,
    const float* __restrict__ WV, const float* __restrict__ WVs, float* __restrict__ mid) {
  // grid (H_, 2)
  __shared__ float As[64*68];
  __shared__ float Bs[64*68];
  const int h = blockIdx.x, vt = blockIdx.y, t = threadIdx.x;
  const int tb = t & 15, tr2 = t >> 4;
  float acc[4][4] = {};
  for (int k0=0;k0<R_;k0+=64) {
    #pragma unroll
    for (int l=0;l<4;l++) {
      int idx = t + l*256;
      int row = idx >> 4, c4 = idx & 15;
      *reinterpret_cast<float4*>(&As[row*68 + c4*4]) = ld4(&obuf[((size_t)row*H_+h)*R_ + k0 + c4*4]);
      *reinterpret_cast<float4*>(&Bs[row*68 + c4*4]) = ld4(&WV[((size_t)h*V_ + vt*64 + row)*R_ + k0 + c4*4]);
    }
    __syncthreads();
    #pragma unroll
    for (int k=0;k<64;k++) {
      float a[4], bb[4];
      #pragma unroll
      for (int i=0;i<4;i++) a[i] = As[(tb+16*i)*68 + k];
      #pragma unroll
      for (int j=0;j<4;j++) bb[j] = Bs[(tr2+16*j)*68 + k];
      #pragma unroll
      for (int i=0;i<4;i++)
        #pragma unroll
        for (int j=0;j<4;j++) acc[i][j] += a[i]*bb[j];
    }
    __syncthreads();
  }
  const float sc = WVs[0];
  #pragma unroll
  for (int i=0;i<4;i++)
    #pragma unroll
    for (int j=0;j<4;j++)
      mid[(size_t)(tb+16*i)*HID_ + h*V_ + vt*64 + tr2 + 16*j] = acc[i][j]*sc;
}

// ---------------- final reduce of Wo partials ----------------
__global__ __launch_bounds__(256) void reduce_out(const float* __restrict__ op2, float* __restrict__ out) {
  int idx = blockIdx.x*256 + threadIdx.x; // float4 index
  float4 s = make_float4(0.f,0.f,0.f,0.f);
  #pragma unroll
  for (int c=0;c<KCH_;c++) {
    float4 v = ld4(&op2[(size_t)c*B_*HID_ + (size_t)idx*4]);
    s.x+=v.x; s.y+=v.y; s.z+=v.z; s.w+=v.w;
  }
  *reinterpret_cast<float4*>(&out[(size_t)idx*4]) = s;
}

extern "C" void kernel_launch(void* const* d_in, const int* in_sizes, int n_in,
                              void* d_out, int out_size, void* d_ws, size_t ws_size,
                              hipStream_t stream) {
  (void)in_sizes; (void)n_in; (void)out_size; (void)ws_size;
  const float* x   = (const float*)d_in[0];
  const float* Wq  = (const float*)d_in[1];
  const float* WK  = (const float*)d_in[2];
  const float* WKs = (const float*)d_in[3];
  const float* WV  = (const float*)d_in[4];
  const float* WVs = (const float*)d_in[5];
  const float* Wo  = (const float*)d_in[6];
  const float* kv  = (const float*)d_in[7];
  const int* topk  = (const int*)d_in[8];
  const int* pos   = (const int*)d_in[9];
  float* ws = (float*)d_ws;
  float* qp    = ws;                                   // 8*64*6144    = 3,145,728
  float* qn    = qp    + (size_t)8*64*6144;            // 64*32*128    =   262,144
  float* qfull = qn    + (size_t)64*32*128;            // 64*32*576    = 1,179,648
  float* om    = qfull + (size_t)64*32*576;            // 64*8*32
  float* ol    = om    + (size_t)64*8*32;              // 64*8*32
  float* op    = ol    + (size_t)64*8*32;              // 64*8*32*512  = 8,388,608
  float* obuf  = op    + (size_t)64*8*32*512;          // 64*32*512    = 1,048,576
  float* mid   = obuf  + (size_t)64*32*512;            // 64*4096      =   262,144
  float* op2   = mid   + (size_t)64*4096;              // 8*64*4096    = 2,097,152
  float* outf  = (float*)d_out;

  gemm64_partial<<<dim3(48,8),256,0,stream>>>(x, Wq, qp, NQ_, HID_);
  reduce_rope<<<64,256,0,stream>>>(qp, pos, qn, qfull);
  ql_gemm<<<dim3(32,8),256,0,stream>>>(qn, WK, WKs, qfull);
  attn_chunk<<<dim3(8,64),256,0,stream>>>(qfull, kv, topk, om, ol, op);
  attn_merge<<<2048,128,0,stream>>>(om, ol, op, obuf);
  vproj<<<dim3(32,2),256,0,stream>>>(obuf, WV, WVs, mid);
  gemm64_partial<<<dim3(32,8),256,0,stream>>>(mid, Wo, op2, HID_, HID_);
  reduce_out<<<256,256,0,stream>>>(op2, outf);
}

// Round 4
// 489.137 us; speedup vs baseline: 10.3462x; 1.0249x over previous
//
#include <hip/hip_runtime.h>
#include <hip/hip_bf16.h>
#include <math.h>

#define H_ 32
#define R_ 512
#define NOPE_ 128
#define ROPE_ 64
#define V_ 128
#define HID_ 4096
#define B_ 64
#define S_ 4096
#define TOPK_ 2048
#define DQ_ 192      // NOPE+ROPE
#define NQ_ 6144     // H*DQ
#define DKV_ 576     // R+ROPE
#define KCH_ 8       // K-chunks for partial skinny GEMMs
#define ACH_ 8       // attention k-chunks
#define CHUNK_ 256   // TOPK/ACH
#define TILE_ 32     // gathered rows per inner iteration
#define KPAD_ 584    // padded row stride in LDS bf16 elements (584*2B = 73*16B)

typedef __attribute__((ext_vector_type(8))) short bf16x8;
typedef __attribute__((ext_vector_type(4))) float f32x4;

__device__ __forceinline__ float4 ld4(const float* p) { return *reinterpret_cast<const float4*>(p); }
__device__ __forceinline__ short f2b(float f) {
  __hip_bfloat16 h = __float2bfloat16(f);
  short s; __builtin_memcpy(&s, &h, 2); return s;
}
__device__ __forceinline__ float b2f(short s) {
  union { unsigned u; float f; } x; x.u = ((unsigned)(unsigned short)s) << 16; return x.f;
}

// ---------------- skinny partial GEMM: C_partial[kc] = A(64 x Kchunk) @ B ----------------
__global__ __launch_bounds__(256) void gemm64_partial(const float* __restrict__ A,
    const float* __restrict__ Bm, float* __restrict__ Cp, int N, int K) {
  __shared__ float xs[64*32];
  __shared__ float wsb[32*128];
  const int t = threadIdx.x;
  const int nt = blockIdx.x, kc = blockIdx.y;
  const int n0 = nt*128;
  const int kchunk = K / KCH_;
  const int kbeg = kc*kchunk;
  const int tr = t >> 5, tc = t & 31;
  float4 acc[8];
  #pragma unroll
  for (int i=0;i<8;i++) acc[i] = make_float4(0.f,0.f,0.f,0.f);
  for (int k0 = kbeg; k0 < kbeg + kchunk; k0 += 32) {
    #pragma unroll
    for (int l=0;l<2;l++) {
      int idx = t + l*256;
      int row = idx >> 3, c4 = idx & 7;
      *reinterpret_cast<float4*>(&xs[row*32 + c4*4]) = ld4(&A[(size_t)row*K + k0 + c4*4]);
    }
    #pragma unroll
    for (int l=0;l<4;l++) {
      int idx = t + l*256;
      int kr = idx >> 5, c4 = idx & 31;
      *reinterpret_cast<float4*>(&wsb[kr*128 + c4*4]) = ld4(&Bm[(size_t)(k0+kr)*N + n0 + c4*4]);
    }
    __syncthreads();
    #pragma unroll
    for (int kk=0;kk<32;kk++) {
      float4 bv = *reinterpret_cast<const float4*>(&wsb[kk*128 + tc*4]);
      #pragma unroll
      for (int i=0;i<8;i++) {
        float a = xs[(tr*8+i)*32 + kk];
        acc[i].x += a*bv.x; acc[i].y += a*bv.y; acc[i].z += a*bv.z; acc[i].w += a*bv.w;
      }
    }
    __syncthreads();
  }
  #pragma unroll
  for (int i=0;i<8;i++) {
    int row = tr*8+i;
    *reinterpret_cast<float4*>(&Cp[((size_t)kc*64 + row)*N + n0 + tc*4]) = acc[i];
  }
}

// ---------------- reduce q partials + split nope/pe + rope ----------------
__global__ __launch_bounds__(256) void reduce_rope(const float* __restrict__ qp,
    const int* __restrict__ positions, float* __restrict__ qn, float* __restrict__ qfull) {
  __shared__ float pe[H_*ROPE_];
  const int b = blockIdx.x, t = threadIdx.x;
  for (int n = t*4; n < NQ_; n += 1024) {
    float4 s = make_float4(0.f,0.f,0.f,0.f);
    for (int c=0;c<KCH_;c++) {
      float4 v = ld4(&qp[((size_t)c*64 + b)*NQ_ + n]);
      s.x+=v.x; s.y+=v.y; s.z+=v.z; s.w+=v.w;
    }
    float vs[4] = {s.x,s.y,s.z,s.w};
    #pragma unroll
    for (int e=0;e<4;e++) {
      int nn = n+e; int h = nn/DQ_; int d = nn - h*DQ_;
      if (d < NOPE_) qn[((size_t)b*H_ + h)*NOPE_ + d] = vs[e];
      else pe[h*ROPE_ + (d-NOPE_)] = vs[e];
    }
  }
  __syncthreads();
  const float pos = (float)positions[b];
  const float SC = 0.0721687836487032f; // 1/sqrt(192)
  for (int it = t; it < H_*32; it += 256) {
    int h = it >> 5, i = it & 31;
    float invf = (float)exp(-(double)i * 0.28782313662425574); // 10000^(-i/32)
    float fr = pos * invf;
    float cs = cosf(fr), sn = sinf(fr);
    float q1 = pe[h*ROPE_ + i], q2 = pe[h*ROPE_ + 32 + i];
    qfull[((size_t)b*H_ + h)*DKV_ + R_ + i]      = (q1*cs - q2*sn)*SC;
    qfull[((size_t)b*H_ + h)*DKV_ + R_ + 32 + i] = (q2*cs + q1*sn)*SC;
  }
}

// ---------------- ql = q_nope @ W_K[h]^T, scaled, written into qfull[:, :, 0:512] ----------------
__global__ __launch_bounds__(256) void ql_gemm(const float* __restrict__ qn,
    const float* __restrict__ WK, const float* __restrict__ WKs, float* __restrict__ qfull) {
  __shared__ float As[64*132];
  __shared__ float Bs[64*132];
  const int h = blockIdx.x, rt = blockIdx.y, t = threadIdx.x;
  #pragma unroll
  for (int l=0;l<8;l++) {
    int idx = t + l*256;
    int row = idx >> 5, c4 = idx & 31;
    *reinterpret_cast<float4*>(&As[row*132 + c4*4]) = ld4(&qn[((size_t)row*H_ + h)*NOPE_ + c4*4]);
    *reinterpret_cast<float4*>(&Bs[row*132 + c4*4]) = ld4(&WK[((size_t)h*R_ + rt*64 + row)*NOPE_ + c4*4]);
  }
  __syncthreads();
  const int tb = t & 15, tr2 = t >> 4;
  float acc[4][4] = {};
  for (int k=0;k<NOPE_;k++) {
    float a[4], bb[4];
    #pragma unroll
    for (int i=0;i<4;i++) a[i] = As[(tb+16*i)*132 + k];
    #pragma unroll
    for (int j=0;j<4;j++) bb[j] = Bs[(tr2+16*j)*132 + k];
    #pragma unroll
    for (int i=0;i<4;i++)
      #pragma unroll
      for (int j=0;j<4;j++) acc[i][j] += a[i]*bb[j];
  }
  const float sc = WKs[0] * 0.0721687836487032f;
  #pragma unroll
  for (int i=0;i<4;i++)
    #pragma unroll
    for (int j=0;j<4;j++) {
      int b = tb+16*i, r = rt*64 + tr2 + 16*j;
      qfull[((size_t)b*H_ + h)*DKV_ + r] = acc[i][j]*sc;
    }
}

// ---------------- flash-decode attention chunk: MFMA scores + VALU PV ----------------
// Scores: S_T[key][head] = sum_d K[key][d]*Q[head][d] via mfma_f32_16x16x32_bf16.
//   D layout (m89): n=head=lane&15, m=key=(lane>>4)*4+reg.
//   A frag: lane holds K[key=lane&15][d=(lane>>4)*8+j]  (row-major bf16 LDS, b128)
//   B frag: lane holds Q[head=lane&15][d=(lane>>4)*8+j] (registers, hoisted)
// 4 waves = (wm: head-block 0/1) x (wn: key-block 0/1). Online softmax with
// cross-wave max exchange via LDS; l_run kept per key-half, merged at end.
__global__ __launch_bounds__(256) void attn_chunk(const float* __restrict__ qfull,
    const float* __restrict__ kv, const int* __restrict__ topk,
    float* __restrict__ om, float* __restrict__ ol, float* __restrict__ op) {
  __shared__ __align__(16) short krows[TILE_*KPAD_];  // 32 gathered kv rows, bf16
  __shared__ float P_lds[H_*(TILE_+1)];               // probs for current 32 rows
  __shared__ float sm_max[2*H_];
  __shared__ float sm_sum[2*H_];
  __shared__ float fl[H_];                            // per-head rescale factor
  const int kc = blockIdx.x, b = blockIdx.y, t = threadIdx.x;
  const int lane = t & 63, wid = t >> 6;
  const int wm = wid >> 1, wn = wid & 1;
  const int lk = lane & 15, lg = lane >> 4;
  const int rs = t >> 3, a = t & 7;   // o-phase mapping: r-slice, head-base

  // hoist Q fragments for this wave's 16 heads (bf16, 18 k-steps of 32)
  bf16x8 qf[18];
  {
    const float* qb = &qfull[((size_t)b*H_ + wm*16 + lk)*DKV_];
    #pragma unroll
    for (int ks=0; ks<18; ++ks) {
      float4 u = ld4(qb + ks*32 + lg*8);
      float4 v = ld4(qb + ks*32 + lg*8 + 4);
      bf16x8 f;
      f[0]=f2b(u.x); f[1]=f2b(u.y); f[2]=f2b(u.z); f[3]=f2b(u.w);
      f[4]=f2b(v.x); f[5]=f2b(v.y); f[6]=f2b(v.z); f[7]=f2b(v.w);
      qf[ks] = f;
    }
  }

  float m_run = -INFINITY, l_run = 0.f;   // per (head=wm*16+lk, key-half wn)
  float4 oa[4][4];
  #pragma unroll
  for (int j=0;j<4;j++)
    #pragma unroll
    for (int c=0;c<4;c++) oa[j][c] = make_float4(0.f,0.f,0.f,0.f);
  const int kbase = b*TOPK_ + kc*CHUNK_;

  for (int g=0; g<CHUNK_/TILE_; g++) {
    // ---- gather 32 rows, f32 -> bf16 -> LDS ----
    #pragma unroll
    for (int l=0;l<18;l++) {
      int idx = t + l*256;                 // 32*144 = 4608 = 18*256 exactly
      int row = idx/144, c = idx - row*144;
      int ki = topk[kbase + g*TILE_ + row];
      float4 v = ld4(&kv[((size_t)b*S_ + ki)*DKV_ + c*4]);
      short4 s4;
      s4.x = f2b(v.x); s4.y = f2b(v.y); s4.z = f2b(v.z); s4.w = f2b(v.w);
      *reinterpret_cast<short4*>(&krows[row*KPAD_ + c*4]) = s4;
    }
    __syncthreads();   // B1: krows ready

    // ---- scores via MFMA: this wave's 16x16 S_T tile ----
    f32x4 acc = {0.f, 0.f, 0.f, 0.f};
    #pragma unroll
    for (int ks=0; ks<18; ++ks) {
      bf16x8 af = *reinterpret_cast<const bf16x8*>(&krows[(wn*16+lk)*KPAD_ + ks*32 + lg*8]);
      acc = __builtin_amdgcn_mfma_f32_16x16x32_bf16(af, qf[ks], acc, 0, 0, 0);
    }
    // tile max per head (reduce over 16 keys: 4 regs + lane groups 16,32)
    float tmax = fmaxf(fmaxf(acc[0],acc[1]), fmaxf(acc[2],acc[3]));
    tmax = fmaxf(tmax, __shfl_xor(tmax, 16));
    tmax = fmaxf(tmax, __shfl_xor(tmax, 32));
    if (lane < 16) sm_max[wn*H_ + wm*16 + lane] = tmax;
    __syncthreads();   // B2: both halves' maxima ready

    float other = sm_max[(wn^1)*H_ + wm*16 + lk];
    float m_new = fmaxf(m_run, fmaxf(tmax, other));
    float fscale = __expf(m_run - m_new);
    m_run = m_new;
    float p0 = __expf(acc[0]-m_new), p1 = __expf(acc[1]-m_new);
    float p2 = __expf(acc[2]-m_new), p3 = __expf(acc[3]-m_new);
    float ps = (p0+p1)+(p2+p3);
    ps += __shfl_xor(ps, 16);
    ps += __shfl_xor(ps, 32);
    l_run = l_run*fscale + ps;
    {
      float* pr = &P_lds[(wm*16+lk)*(TILE_+1) + wn*16 + lg*4];
      pr[0]=p0; pr[1]=p1; pr[2]=p2; pr[3]=p3;
    }
    if (wn==0 && lane<16) fl[wm*16+lane] = fscale;
    __syncthreads();   // B3: P_lds + fl ready

    // ---- o accumulate (VALU f32, bf16 rows): thread owns heads {a+8j}, slot c = col (c+rs)&3
    float fj[4];
    #pragma unroll
    for (int j=0;j<4;j++) fj[j] = fl[a+8*j];
    #pragma unroll
    for (int j=0;j<4;j++)
      #pragma unroll
      for (int c=0;c<4;c++) { oa[j][c].x*=fj[j]; oa[j][c].y*=fj[j]; oa[j][c].z*=fj[j]; oa[j][c].w*=fj[j]; }
    #pragma unroll
    for (int kk=0;kk<TILE_;kk++) {
      float p4[4];
      #pragma unroll
      for (int j=0;j<4;j++) p4[j] = P_lds[(a+8*j)*(TILE_+1) + kk];
      #pragma unroll
      for (int c=0;c<4;c++) {
        const int qc = (c+rs)&3;   // runtime ADDRESS rotation, static REGISTER index
        short4 rv = *reinterpret_cast<const short4*>(&krows[kk*KPAD_ + rs*16 + qc*4]);
        float vx = b2f(rv.x), vy = b2f(rv.y), vz = b2f(rv.z), vw = b2f(rv.w);
        #pragma unroll
        for (int j=0;j<4;j++) {
          oa[j][c].x += p4[j]*vx; oa[j][c].y += p4[j]*vy; oa[j][c].z += p4[j]*vz; oa[j][c].w += p4[j]*vw;
        }
      }
    }
    __syncthreads();   // B4: o done, krows free for next gather
  }

  // merge l_run halves, write stats
  if (lane < 16) sm_sum[wn*H_ + wm*16 + lane] = l_run;
  __syncthreads();
  if (wn==0 && lane<16) {
    int h = wm*16 + lane;
    om[(b*ACH_+kc)*H_ + h] = m_run;
    ol[(b*ACH_+kc)*H_ + h] = sm_sum[0*H_+h] + sm_sum[1*H_+h];
  }
  #pragma unroll
  for (int j=0;j<4;j++)
    #pragma unroll
    for (int c=0;c<4;c++) {
      const int qc = (c+rs)&3;
      *reinterpret_cast<float4*>(&op[(((size_t)(b*ACH_+kc))*H_ + a+8*j)*R_ + rs*16 + qc*4]) = oa[j][c];
    }
}

// ---------------- merge chunk partials ----------------
__global__ __launch_bounds__(128) void attn_merge(const float* __restrict__ om,
    const float* __restrict__ ol, const float* __restrict__ op, float* __restrict__ obuf) {
  const int bh = blockIdx.x;
  const int b = bh >> 5, h = bh & 31;
  const int t = threadIdx.x;
  float mv[8], lv[8], w[8];
  float M = -INFINITY;
  #pragma unroll
  for (int c=0;c<8;c++) { mv[c] = om[(b*ACH_+c)*H_ + h]; lv[c] = ol[(b*ACH_+c)*H_+h]; M = fmaxf(M, mv[c]); }
  float L = 0.f;
  #pragma unroll
  for (int c=0;c<8;c++) { w[c] = __expf(mv[c]-M); L += lv[c]*w[c]; }
  float inv = 1.0f / L;
  float4 s = make_float4(0.f,0.f,0.f,0.f);
  #pragma unroll
  for (int c=0;c<8;c++) {
    float4 v = ld4(&op[(((size_t)(b*ACH_+c))*H_ + h)*R_ + t*4]);
    s.x += v.x*w[c]; s.y += v.y*w[c]; s.z += v.z*w[c]; s.w += v.w*w[c];
  }
  s.x*=inv; s.y*=inv; s.z*=inv; s.w*=inv;
  *reinterpret_cast<float4*>(&obuf[((size_t)b*H_+h)*R_ + t*4]) = s;
}

// ---------------- out = o @ W_V[h]^T * scale ----------------
__global__ __launch_bounds__(256) void vproj(const float* __restrict__ obuf,
    const float* __restrict__ WV, const float* __restrict__ WVs, float* __restrict__ mid) {
  __shared__ float As[64*68];
  __shared__ float Bs[64*68];
  const int h = blockIdx.x, vt = blockIdx.y, t = threadIdx.x;
  const int tb = t & 15, tr2 = t >> 4;
  float acc[4][4] = {};
  for (int k0=0;k0<R_;k0+=64) {
    #pragma unroll
    for (int l=0;l<4;l++) {
      int idx = t + l*256;
      int row = idx >> 4, c4 = idx & 15;
      *reinterpret_cast<float4*>(&As[row*68 + c4*4]) = ld4(&obuf[((size_t)row*H_+h)*R_ + k0 + c4*4]);
      *reinterpret_cast<float4*>(&Bs[row*68 + c4*4]) = ld4(&WV[((size_t)h*V_ + vt*64 + row)*R_ + k0 + c4*4]);
    }
    __syncthreads();
    #pragma unroll
    for (int k=0;k<64;k++) {
      float a[4], bb[4];
      #pragma unroll
      for (int i=0;i<4;i++) a[i] = As[(tb+16*i)*68 + k];
      #pragma unroll
      for (int j=0;j<4;j++) bb[j] = Bs[(tr2+16*j)*68 + k];
      #pragma unroll
      for (int i=0;i<4;i++)
        #pragma unroll
        for (int j=0;j<4;j++) acc[i][j] += a[i]*bb[j];
    }
    __syncthreads();
  }
  const float sc = WVs[0];
  #pragma unroll
  for (int i=0;i<4;i++)
    #pragma unroll
    for (int j=0;j<4;j++)
      mid[(size_t)(tb+16*i)*HID_ + h*V_ + vt*64 + tr2 + 16*j] = acc[i][j]*sc;
}

// ---------------- final reduce of Wo partials ----------------
__global__ __launch_bounds__(256) void reduce_out(const float* __restrict__ op2, float* __restrict__ out) {
  int idx = blockIdx.x*256 + threadIdx.x; // float4 index
  float4 s = make_float4(0.f,0.f,0.f,0.f);
  #pragma unroll
  for (int c=0;c<KCH_;c++) {
    float4 v = ld4(&op2[(size_t)c*B_*HID_ + (size_t)idx*4]);
    s.x+=v.x; s.y+=v.y; s.z+=v.z; s.w+=v.w;
  }
  *reinterpret_cast<float4*>(&out[(size_t)idx*4]) = s;
}

extern "C" void kernel_launch(void* const* d_in, const int* in_sizes, int n_in,
                              void* d_out, int out_size, void* d_ws, size_t ws_size,
                              hipStream_t stream) {
  (void)in_sizes; (void)n_in; (void)out_size; (void)ws_size;
  const float* x   = (const float*)d_in[0];
  const float* Wq  = (const float*)d_in[1];
  const float* WK  = (const float*)d_in[2];
  const float* WKs = (const float*)d_in[3];
  const float* WV  = (const float*)d_in[4];
  const float* WVs = (const float*)d_in[5];
  const float* Wo  = (const float*)d_in[6];
  const float* kv  = (const float*)d_in[7];
  const int* topk  = (const int*)d_in[8];
  const int* pos   = (const int*)d_in[9];
  float* ws = (float*)d_ws;
  float* qp    = ws;                                   // 8*64*6144    = 3,145,728
  float* qn    = qp    + (size_t)8*64*6144;            // 64*32*128    =   262,144
  float* qfull = qn    + (size_t)64*32*128;            // 64*32*576    = 1,179,648
  float* om    = qfull + (size_t)64*32*576;            // 64*8*32
  float* ol    = om    + (size_t)64*8*32;              // 64*8*32
  float* op    = ol    + (size_t)64*8*32;              // 64*8*32*512  = 8,388,608
  float* obuf  = op    + (size_t)64*8*32*512;          // 64*32*512    = 1,048,576
  float* mid   = obuf  + (size_t)64*32*512;            // 64*4096      =   262,144
  float* op2   = mid   + (size_t)64*4096;              // 8*64*4096    = 2,097,152
  float* outf  = (float*)d_out;

  gemm64_partial<<<dim3(48,8),256,0,stream>>>(x, Wq, qp, NQ_, HID_);
  reduce_rope<<<64,256,0,stream>>>(qp, pos, qn, qfull);
  ql_gemm<<<dim3(32,8),256,0,stream>>>(qn, WK, WKs, qfull);
  attn_chunk<<<dim3(8,64),256,0,stream>>>(qfull, kv, topk, om, ol, op);
  attn_merge<<<2048,128,0,stream>>>(om, ol, op, obuf);
  vproj<<<dim3(32,2),256,0,stream>>>(obuf, WV, WVs, mid);
  gemm64_partial<<<dim3(32,8),256,0,stream>>>(mid, Wo, op2, HID_, HID_);
  reduce_out<<<256,256,0,stream>>>(op2, outf);
}

// Round 5
// 290.240 us; speedup vs baseline: 17.4363x; 1.6853x over previous
//
#include <hip/hip_runtime.h>
#include <hip/hip_bf16.h>
#include <math.h>

#define H_ 32
#define R_ 512
#define NOPE_ 128
#define ROPE_ 64
#define V_ 128
#define HID_ 4096
#define B_ 64
#define S_ 4096
#define TOPK_ 2048
#define DQ_ 192      // NOPE+ROPE
#define NQ_ 6144     // H*DQ
#define DKV_ 576     // R+ROPE
#define KCH_ 8       // K-chunks for partial skinny GEMMs
#define ACH_ 8       // attention k-chunks
#define CHUNK_ 256   // TOPK/ACH
#define TILE_ 16     // gathered rows per inner iteration
#define KPAD_ 584    // padded krows stride (shorts); 584*2=1168B = 73*16 -> 16B aligned
#define VTS_ 24      // vT stride (shorts); 48B -> 16B aligned
#define NG_ (CHUNK_/TILE_)   // 16 inner iterations

typedef __attribute__((ext_vector_type(8))) short bf16x8;
typedef __attribute__((ext_vector_type(4))) float f32x4;
typedef __attribute__((ext_vector_type(16))) float f32x16;

__device__ __forceinline__ float4 ld4(const float* p) { return *reinterpret_cast<const float4*>(p); }
__device__ __forceinline__ short f2b(float f) {
  __hip_bfloat16 h = __float2bfloat16(f);
  short s; __builtin_memcpy(&s, &h, 2); return s;
}

// ---------------- skinny partial GEMM: C_partial[kc] = A(64 x Kchunk) @ B ----------------
__global__ __launch_bounds__(256) void gemm64_partial(const float* __restrict__ A,
    const float* __restrict__ Bm, float* __restrict__ Cp, int N, int K) {
  __shared__ float xs[64*32];
  __shared__ float wsb[32*128];
  const int t = threadIdx.x;
  const int nt = blockIdx.x, kc = blockIdx.y;
  const int n0 = nt*128;
  const int kchunk = K / KCH_;
  const int kbeg = kc*kchunk;
  const int tr = t >> 5, tc = t & 31;
  float4 acc[8];
  #pragma unroll
  for (int i=0;i<8;i++) acc[i] = make_float4(0.f,0.f,0.f,0.f);
  for (int k0 = kbeg; k0 < kbeg + kchunk; k0 += 32) {
    #pragma unroll
    for (int l=0;l<2;l++) {
      int idx = t + l*256;
      int row = idx >> 3, c4 = idx & 7;
      *reinterpret_cast<float4*>(&xs[row*32 + c4*4]) = ld4(&A[(size_t)row*K + k0 + c4*4]);
    }
    #pragma unroll
    for (int l=0;l<4;l++) {
      int idx = t + l*256;
      int kr = idx >> 5, c4 = idx & 31;
      *reinterpret_cast<float4*>(&wsb[kr*128 + c4*4]) = ld4(&Bm[(size_t)(k0+kr)*N + n0 + c4*4]);
    }
    __syncthreads();
    #pragma unroll
    for (int kk=0;kk<32;kk++) {
      float4 bv = *reinterpret_cast<const float4*>(&wsb[kk*128 + tc*4]);
      #pragma unroll
      for (int i=0;i<8;i++) {
        float a = xs[(tr*8+i)*32 + kk];
        acc[i].x += a*bv.x; acc[i].y += a*bv.y; acc[i].z += a*bv.z; acc[i].w += a*bv.w;
      }
    }
    __syncthreads();
  }
  #pragma unroll
  for (int i=0;i<8;i++) {
    int row = tr*8+i;
    *reinterpret_cast<float4*>(&Cp[((size_t)kc*64 + row)*N + n0 + tc*4]) = acc[i];
  }
}

// ---------------- reduce q partials + split nope/pe + rope ----------------
__global__ __launch_bounds__(256) void reduce_rope(const float* __restrict__ qp,
    const int* __restrict__ positions, float* __restrict__ qn, float* __restrict__ qfull) {
  __shared__ float pe[H_*ROPE_];
  const int b = blockIdx.x, t = threadIdx.x;
  for (int n = t*4; n < NQ_; n += 1024) {
    float4 s = make_float4(0.f,0.f,0.f,0.f);
    for (int c=0;c<KCH_;c++) {
      float4 v = ld4(&qp[((size_t)c*64 + b)*NQ_ + n]);
      s.x+=v.x; s.y+=v.y; s.z+=v.z; s.w+=v.w;
    }
    float vs[4] = {s.x,s.y,s.z,s.w};
    #pragma unroll
    for (int e=0;e<4;e++) {
      int nn = n+e; int h = nn/DQ_; int d = nn - h*DQ_;
      if (d < NOPE_) qn[((size_t)b*H_ + h)*NOPE_ + d] = vs[e];
      else pe[h*ROPE_ + (d-NOPE_)] = vs[e];
    }
  }
  __syncthreads();
  const float pos = (float)positions[b];
  const float SC = 0.0721687836487032f; // 1/sqrt(192)
  for (int it = t; it < H_*32; it += 256) {
    int h = it >> 5, i = it & 31;
    float invf = (float)exp(-(double)i * 0.28782313662425574); // 10000^(-i/32)
    float fr = pos * invf;
    float cs = cosf(fr), sn = sinf(fr);
    float q1 = pe[h*ROPE_ + i], q2 = pe[h*ROPE_ + 32 + i];
    qfull[((size_t)b*H_ + h)*DKV_ + R_ + i]      = (q1*cs - q2*sn)*SC;
    qfull[((size_t)b*H_ + h)*DKV_ + R_ + 32 + i] = (q2*cs + q1*sn)*SC;
  }
}

// ---------------- ql = q_nope @ W_K[h]^T, scaled, written into qfull[:, :, 0:512] ----------------
__global__ __launch_bounds__(256) void ql_gemm(const float* __restrict__ qn,
    const float* __restrict__ WK, const float* __restrict__ WKs, float* __restrict__ qfull) {
  __shared__ float As[64*132];
  __shared__ float Bs[64*132];
  const int h = blockIdx.x, rt = blockIdx.y, t = threadIdx.x;
  #pragma unroll
  for (int l=0;l<8;l++) {
    int idx = t + l*256;
    int row = idx >> 5, c4 = idx & 31;
    *reinterpret_cast<float4*>(&As[row*132 + c4*4]) = ld4(&qn[((size_t)row*H_ + h)*NOPE_ + c4*4]);
    *reinterpret_cast<float4*>(&Bs[row*132 + c4*4]) = ld4(&WK[((size_t)h*R_ + rt*64 + row)*NOPE_ + c4*4]);
  }
  __syncthreads();
  const int tb = t & 15, tr2 = t >> 4;
  float acc[4][4] = {};
  for (int k=0;k<NOPE_;k++) {
    float a[4], bb[4];
    #pragma unroll
    for (int i=0;i<4;i++) a[i] = As[(tb+16*i)*132 + k];
    #pragma unroll
    for (int j=0;j<4;j++) bb[j] = Bs[(tr2+16*j)*132 + k];
    #pragma unroll
    for (int i=0;i<4;i++)
      #pragma unroll
      for (int j=0;j<4;j++) acc[i][j] += a[i]*bb[j];
  }
  const float sc = WKs[0] * 0.0721687836487032f;
  #pragma unroll
  for (int i=0;i<4;i++)
    #pragma unroll
    for (int j=0;j<4;j++) {
      int b = tb+16*i, r = rt*64 + tr2 + 16*j;
      qfull[((size_t)b*H_ + h)*DKV_ + r] = acc[i][j]*sc;
    }
}

// ---------------- gather 16 kv rows, f32 -> bf16 -> d-major LDS ----------------
__device__ __forceinline__ void gather16(const float* __restrict__ kv,
    const int* __restrict__ topk, int kbase, int g, int b, int t, short* krows) {
  #pragma unroll
  for (int l=0;l<9;l++) {
    int idx = t + l*256;                 // 16*144 = 2304 = 9*256
    int row = idx/144, c = idx - row*144;
    int ki = topk[kbase + g*TILE_ + row];
    float4 v = ld4(&kv[((size_t)b*S_ + ki)*DKV_ + c*4]);
    short4 s4; s4.x=f2b(v.x); s4.y=f2b(v.y); s4.z=f2b(v.z); s4.w=f2b(v.w);
    *reinterpret_cast<short4*>(&krows[row*KPAD_ + c*4]) = s4;
  }
}

// ---------------- flash-decode attention chunk: full-MFMA (scores + PV) ----------------
// Scores (16x16x32, verified map: D col=lane&15=head, row=(lane>>4)*4+reg=key):
//   wave (wm,dn): heads wm*16.., d-half dn*288; partials summed via Spart LDS.
// PV (32x32x16, verified map: D col=lane&31=head, row=(reg&3)+8*(reg>>2)+4*(lane>>5)):
//   A = vT (k-major V copy built by an LDS transpose phase), B = P (bf16).
// Softmax state (m,l) lives in registers (score lane owns head lk; factor is
// lane-uniform for PV via fl[32]). gather(g+1) issues inside the softmax phase.
__global__ __launch_bounds__(256) void attn_chunk(const float* __restrict__ qfull,
    const float* __restrict__ kv, const int* __restrict__ topk,
    float* __restrict__ om, float* __restrict__ ol, float* __restrict__ op) {
  __shared__ __align__(16) short krows[TILE_*KPAD_];   // 18,688 B d-major
  __shared__ __align__(16) short vT[DKV_*VTS_];        // 27,648 B k-major
  __shared__ __align__(16) short P_lds[H_*VTS_];       // 1,536 B
  __shared__ float Spart[2*TILE_*33];                  // 4,224 B
  __shared__ float fl[H_];
  const int kc = blockIdx.x, b = blockIdx.y, t = threadIdx.x;
  const int lane = t & 63, wid = t >> 6;
  const int wm = wid >> 1, dn = wid & 1;   // score role: head-block, d-half
  const int lk = lane & 15, lg = lane >> 4;
  const int l31 = lane & 31, hi = lane >> 5;
  const int tk = t & 15, tg = t >> 4;      // transpose role: key, d-group of 36
  const int h16 = wm*16 + lk;

  // hoist Q fragments: head h16, d = dn*288 + ks*32 + lg*8
  bf16x8 qf[9];
  {
    const float* qb = &qfull[((size_t)b*H_ + h16)*DKV_ + dn*288 + lg*8];
    #pragma unroll
    for (int ks=0; ks<9; ++ks) {
      float4 u = ld4(qb + ks*32);
      float4 v = ld4(qb + ks*32 + 4);
      bf16x8 f;
      f[0]=f2b(u.x); f[1]=f2b(u.y); f[2]=f2b(u.z); f[3]=f2b(u.w);
      f[4]=f2b(v.x); f[5]=f2b(v.y); f[6]=f2b(v.z); f[7]=f2b(v.w);
      qf[ks] = f;
    }
  }

  float m_run = -INFINITY, l_run = 0.f;   // per head h16 (dup across dn; identical)
  f32x16 acc[4];
  #pragma unroll
  for (int tt=0;tt<4;tt++)
    #pragma unroll
    for (int i=0;i<16;i++) acc[tt][i] = 0.f;

  const int kbase = b*TOPK_ + kc*CHUNK_;
  gather16(kv, topk, kbase, 0, b, t, krows);
  __syncthreads();

  for (int g=0; g<NG_; g++) {
    // ---- phase A: score partials (MFMA) + build k-major vT ----
    f32x4 sacc = {0.f,0.f,0.f,0.f};
    #pragma unroll
    for (int ks=0; ks<9; ++ks) {
      bf16x8 af = *reinterpret_cast<const bf16x8*>(&krows[lk*KPAD_ + dn*288 + ks*32 + lg*8]);
      sacc = __builtin_amdgcn_mfma_f32_16x16x32_bf16(af, qf[ks], sacc, 0, 0, 0);
    }
    #pragma unroll
    for (int r=0;r<4;r++)
      Spart[dn*528 + (lg*4+r)*33 + h16] = sacc[r];
    // transpose: thread (tk=key, tg covers d = tg*36 .. +35)
    #pragma unroll
    for (int s9=0; s9<9; ++s9) {
      short4 k4 = *reinterpret_cast<const short4*>(&krows[tk*KPAD_ + tg*36 + s9*4]);
      vT[(tg*36 + s9*4 + 0)*VTS_ + tk] = k4.x;
      vT[(tg*36 + s9*4 + 1)*VTS_ + tk] = k4.y;
      vT[(tg*36 + s9*4 + 2)*VTS_ + tk] = k4.z;
      vT[(tg*36 + s9*4 + 3)*VTS_ + tk] = k4.w;
    }
    __syncthreads();   // B2: Spart + vT ready; krows dead

    // ---- phase B: softmax (regs) + write P/fl + gather(g+1) ----
    float sfull[4];
    #pragma unroll
    for (int r=0;r<4;r++)
      sfull[r] = Spart[(lg*4+r)*33 + h16] + Spart[528 + (lg*4+r)*33 + h16];
    float tmax = fmaxf(fmaxf(sfull[0],sfull[1]), fmaxf(sfull[2],sfull[3]));
    tmax = fmaxf(tmax, __shfl_xor(tmax, 16));
    tmax = fmaxf(tmax, __shfl_xor(tmax, 32));
    float m_new = fmaxf(m_run, tmax);
    float fscale = __expf(m_run - m_new);
    m_run = m_new;
    float p0 = __expf(sfull[0]-m_new), p1 = __expf(sfull[1]-m_new);
    float p2 = __expf(sfull[2]-m_new), p3 = __expf(sfull[3]-m_new);
    float ps = (p0+p1)+(p2+p3);
    ps += __shfl_xor(ps, 16);
    ps += __shfl_xor(ps, 32);
    l_run = l_run*fscale + ps;
    if (dn==0) {
      short4 pk; pk.x=f2b(p0); pk.y=f2b(p1); pk.z=f2b(p2); pk.w=f2b(p3);
      *reinterpret_cast<short4*>(&P_lds[h16*VTS_ + lg*4]) = pk;
      if (lg==0) fl[h16] = fscale;
    }
    if (g < NG_-1) gather16(kv, topk, kbase, g+1, b, t, krows);
    __syncthreads();   // B3: P_lds + fl + krows(g+1) ready

    // ---- phase C: PV via 32x32x16 MFMA; wave owns r in [wid*128, wid*128+128) ----
    float fsc = fl[l31];
    bf16x8 pf = *reinterpret_cast<const bf16x8*>(&P_lds[l31*VTS_ + hi*8]);
    #pragma unroll
    for (int tt=0;tt<4;tt++) {
      #pragma unroll
      for (int i=0;i<16;i++) acc[tt][i] *= fsc;
      bf16x8 vf = *reinterpret_cast<const bf16x8*>(&vT[(wid*128 + tt*32 + l31)*VTS_ + hi*8]);
      acc[tt] = __builtin_amdgcn_mfma_f32_32x32x16_bf16(vf, pf, acc[tt], 0, 0, 0);
    }
    __syncthreads();   // B4: vT free for next transpose
  }

  // stats
  if (dn==0 && lg==0) {
    om[(b*ACH_+kc)*H_ + h16] = m_run;
    ol[(b*ACH_+kc)*H_ + h16] = l_run;
  }
  // o write: lane holds head h=l31, rows r = wid*128 + tt*32 + 8q + 4*hi + (0..3)
  #pragma unroll
  for (int tt=0;tt<4;tt++)
    #pragma unroll
    for (int q=0;q<4;q++) {
      float4 v = make_float4(acc[tt][4*q+0], acc[tt][4*q+1], acc[tt][4*q+2], acc[tt][4*q+3]);
      int r0 = wid*128 + tt*32 + 8*q + 4*hi;
      *reinterpret_cast<float4*>(&op[(((size_t)(b*ACH_+kc))*H_ + l31)*R_ + r0]) = v;
    }
}

// ---------------- merge chunk partials ----------------
__global__ __launch_bounds__(128) void attn_merge(const float* __restrict__ om,
    const float* __restrict__ ol, const float* __restrict__ op, float* __restrict__ obuf) {
  const int bh = blockIdx.x;
  const int b = bh >> 5, h = bh & 31;
  const int t = threadIdx.x;
  float mv[8], lv[8], w[8];
  float M = -INFINITY;
  #pragma unroll
  for (int c=0;c<8;c++) { mv[c] = om[(b*ACH_+c)*H_ + h]; lv[c] = ol[(b*ACH_+c)*H_+h]; M = fmaxf(M, mv[c]); }
  float L = 0.f;
  #pragma unroll
  for (int c=0;c<8;c++) { w[c] = __expf(mv[c]-M); L += lv[c]*w[c]; }
  float inv = 1.0f / L;
  float4 s = make_float4(0.f,0.f,0.f,0.f);
  #pragma unroll
  for (int c=0;c<8;c++) {
    float4 v = ld4(&op[(((size_t)(b*ACH_+c))*H_ + h)*R_ + t*4]);
    s.x += v.x*w[c]; s.y += v.y*w[c]; s.z += v.z*w[c]; s.w += v.w*w[c];
  }
  s.x*=inv; s.y*=inv; s.z*=inv; s.w*=inv;
  *reinterpret_cast<float4*>(&obuf[((size_t)b*H_+h)*R_ + t*4]) = s;
}

// ---------------- out = o @ W_V[h]^T * scale ----------------
__global__ __launch_bounds__(256) void vproj(const float* __restrict__ obuf,
    const float* __restrict__ WV, const float* __restrict__ WVs, float* __restrict__ mid) {
  __shared__ float As[64*68];
  __shared__ float Bs[64*68];
  const int h = blockIdx.x, vt = blockIdx.y, t = threadIdx.x;
  const int tb = t & 15, tr2 = t >> 4;
  float acc[4][4] = {};
  for (int k0=0;k0<R_;k0+=64) {
    #pragma unroll
    for (int l=0;l<4;l++) {
      int idx = t + l*256;
      int row = idx >> 4, c4 = idx & 15;
      *reinterpret_cast<float4*>(&As[row*68 + c4*4]) = ld4(&obuf[((size_t)row*H_+h)*R_ + k0 + c4*4]);
      *reinterpret_cast<float4*>(&Bs[row*68 + c4*4]) = ld4(&WV[((size_t)h*V_ + vt*64 + row)*R_ + k0 + c4*4]);
    }
    __syncthreads();
    #pragma unroll
    for (int k=0;k<64;k++) {
      float a[4], bb[4];
      #pragma unroll
      for (int i=0;i<4;i++) a[i] = As[(tb+16*i)*68 + k];
      #pragma unroll
      for (int j=0;j<4;j++) bb[j] = Bs[(tr2+16*j)*68 + k];
      #pragma unroll
      for (int i=0;i<4;i++)
        #pragma unroll
        for (int j=0;j<4;j++) acc[i][j] += a[i]*bb[j];
    }
    __syncthreads();
  }
  const float sc = WVs[0];
  #pragma unroll
  for (int i=0;i<4;i++)
    #pragma unroll
    for (int j=0;j<4;j++)
      mid[(size_t)(tb+16*i)*HID_ + h*V_ + vt*64 + tr2 + 16*j] = acc[i][j]*sc;
}

// ---------------- final reduce of Wo partials ----------------
__global__ __launch_bounds__(256) void reduce_out(const float* __restrict__ op2, float* __restrict__ out) {
  int idx = blockIdx.x*256 + threadIdx.x; // float4 index
  float4 s = make_float4(0.f,0.f,0.f,0.f);
  #pragma unroll
  for (int c=0;c<KCH_;c++) {
    float4 v = ld4(&op2[(size_t)c*B_*HID_ + (size_t)idx*4]);
    s.x+=v.x; s.y+=v.y; s.z+=v.z; s.w+=v.w;
  }
  *reinterpret_cast<float4*>(&out[(size_t)idx*4]) = s;
}

extern "C" void kernel_launch(void* const* d_in, const int* in_sizes, int n_in,
                              void* d_out, int out_size, void* d_ws, size_t ws_size,
                              hipStream_t stream) {
  (void)in_sizes; (void)n_in; (void)out_size; (void)ws_size;
  const float* x   = (const float*)d_in[0];
  const float* Wq  = (const float*)d_in[1];
  const float* WK  = (const float*)d_in[2];
  const float* WKs = (const float*)d_in[3];
  const float* WV  = (const float*)d_in[4];
  const float* WVs = (const float*)d_in[5];
  const float* Wo  = (const float*)d_in[6];
  const float* kv  = (const float*)d_in[7];
  const int* topk  = (const int*)d_in[8];
  const int* pos   = (const int*)d_in[9];
  float* ws = (float*)d_ws;
  float* qp    = ws;                                   // 8*64*6144    = 3,145,728
  float* qn    = qp    + (size_t)8*64*6144;            // 64*32*128    =   262,144
  float* qfull = qn    + (size_t)64*32*128;            // 64*32*576    = 1,179,648
  float* om    = qfull + (size_t)64*32*576;            // 64*8*32
  float* ol    = om    + (size_t)64*8*32;              // 64*8*32
  float* op    = ol    + (size_t)64*8*32;              // 64*8*32*512  = 8,388,608
  float* obuf  = op    + (size_t)64*8*32*512;          // 64*32*512    = 1,048,576
  float* mid   = obuf  + (size_t)64*32*512;            // 64*4096      =   262,144
  float* op2   = mid   + (size_t)64*4096;              // 8*64*4096    = 2,097,152
  float* outf  = (float*)d_out;

  gemm64_partial<<<dim3(48,8),256,0,stream>>>(x, Wq, qp, NQ_, HID_);
  reduce_rope<<<64,256,0,stream>>>(qp, pos, qn, qfull);
  ql_gemm<<<dim3(32,8),256,0,stream>>>(qn, WK, WKs, qfull);
  attn_chunk<<<dim3(8,64),256,0,stream>>>(qfull, kv, topk, om, ol, op);
  attn_merge<<<2048,128,0,stream>>>(om, ol, op, obuf);
  vproj<<<dim3(32,2),256,0,stream>>>(obuf, WV, WVs, mid);
  gemm64_partial<<<dim3(32,8),256,0,stream>>>(mid, Wo, op2, HID_, HID_);
  reduce_out<<<256,256,0,stream>>>(op2, outf);
}

// Round 8
// 238.522 us; speedup vs baseline: 21.2170x; 1.2168x over previous
//
#include <hip/hip_runtime.h>
#include <hip/hip_bf16.h>
#include <math.h>

#define H_ 32
#define R_ 512
#define NOPE_ 128
#define ROPE_ 64
#define V_ 128
#define HID_ 4096
#define B_ 64
#define S_ 4096
#define TOPK_ 2048
#define DQ_ 192      // NOPE+ROPE
#define NQ_ 6144     // H*DQ
#define DKV_ 576     // R+ROPE
#define KCH_ 8       // K-chunks for partial skinny GEMMs
#define ACH_ 8       // attention k-chunks
#define CHUNK_ 256   // TOPK/ACH
#define TILE_ 16     // gathered rows per inner iteration
#define NG_ (CHUNK_/TILE_)   // 16 inner iterations
#define DGSTR_ 264   // krows dgrp stride in shorts (16key*16d = 256 + 8 pad)
#define KRSZ_ (36*DGSTR_)    // shorts per buffer
#define VTS_ 24      // P_lds stride (shorts)

typedef __attribute__((ext_vector_type(8))) short bf16x8;
typedef __attribute__((ext_vector_type(4))) short s16x4;
typedef __attribute__((ext_vector_type(4))) float f32x4;
typedef __attribute__((ext_vector_type(16))) float f32x16;

__device__ __forceinline__ float4 ld4(const float* p) { return *reinterpret_cast<const float4*>(p); }
__device__ __forceinline__ short f2b(float f) {
  __hip_bfloat16 h = __float2bfloat16(f);
  short s; __builtin_memcpy(&s, &h, 2); return s;
}
__device__ __forceinline__ s16x4 tr_read(unsigned byte_addr) {
  s16x4 r;
  asm volatile("ds_read_b64_tr_b16 %0, %1" : "=v"(r) : "v"(byte_addr));
  return r;
}

// ---------------- skinny partial GEMM: C_partial[kc] = A(64 x Kchunk) @ B ----------------
__global__ __launch_bounds__(256) void gemm64_partial(const float* __restrict__ A,
    const float* __restrict__ Bm, float* __restrict__ Cp, int N, int K) {
  __shared__ float xs[64*32];
  __shared__ float wsb[32*128];
  const int t = threadIdx.x;
  const int nt = blockIdx.x, kc = blockIdx.y;
  const int n0 = nt*128;
  const int kchunk = K / KCH_;
  const int kbeg = kc*kchunk;
  const int tr = t >> 5, tc = t & 31;
  float4 acc[8];
  #pragma unroll
  for (int i=0;i<8;i++) acc[i] = make_float4(0.f,0.f,0.f,0.f);
  for (int k0 = kbeg; k0 < kbeg + kchunk; k0 += 32) {
    #pragma unroll
    for (int l=0;l<2;l++) {
      int idx = t + l*256;
      int row = idx >> 3, c4 = idx & 7;
      *reinterpret_cast<float4*>(&xs[row*32 + c4*4]) = ld4(&A[(size_t)row*K + k0 + c4*4]);
    }
    #pragma unroll
    for (int l=0;l<4;l++) {
      int idx = t + l*256;
      int kr = idx >> 5, c4 = idx & 31;
      *reinterpret_cast<float4*>(&wsb[kr*128 + c4*4]) = ld4(&Bm[(size_t)(k0+kr)*N + n0 + c4*4]);
    }
    __syncthreads();
    #pragma unroll
    for (int kk=0;kk<32;kk++) {
      float4 bv = *reinterpret_cast<const float4*>(&wsb[kk*128 + tc*4]);
      #pragma unroll
      for (int i=0;i<8;i++) {
        float a = xs[(tr*8+i)*32 + kk];
        acc[i].x += a*bv.x; acc[i].y += a*bv.y; acc[i].z += a*bv.z; acc[i].w += a*bv.w;
      }
    }
    __syncthreads();
  }
  #pragma unroll
  for (int i=0;i<8;i++) {
    int row = tr*8+i;
    *reinterpret_cast<float4*>(&Cp[((size_t)kc*64 + row)*N + n0 + tc*4]) = acc[i];
  }
}

// ---------------- reduce q partials + split nope/pe + rope ----------------
__global__ __launch_bounds__(256) void reduce_rope(const float* __restrict__ qp,
    const int* __restrict__ positions, float* __restrict__ qn, float* __restrict__ qfull) {
  __shared__ float pe[H_*ROPE_];
  const int b = blockIdx.x, t = threadIdx.x;
  for (int n = t*4; n < NQ_; n += 1024) {
    float4 s = make_float4(0.f,0.f,0.f,0.f);
    for (int c=0;c<KCH_;c++) {
      float4 v = ld4(&qp[((size_t)c*64 + b)*NQ_ + n]);
      s.x+=v.x; s.y+=v.y; s.z+=v.z; s.w+=v.w;
    }
    float vs[4] = {s.x,s.y,s.z,s.w};
    #pragma unroll
    for (int e=0;e<4;e++) {
      int nn = n+e; int h = nn/DQ_; int d = nn - h*DQ_;
      if (d < NOPE_) qn[((size_t)b*H_ + h)*NOPE_ + d] = vs[e];
      else pe[h*ROPE_ + (d-NOPE_)] = vs[e];
    }
  }
  __syncthreads();
  const float pos = (float)positions[b];
  const float SC = 0.0721687836487032f; // 1/sqrt(192)
  for (int it = t; it < H_*32; it += 256) {
    int h = it >> 5, i = it & 31;
    float invf = (float)exp(-(double)i * 0.28782313662425574); // 10000^(-i/32)
    float fr = pos * invf;
    float cs = cosf(fr), sn = sinf(fr);
    float q1 = pe[h*ROPE_ + i], q2 = pe[h*ROPE_ + 32 + i];
    qfull[((size_t)b*H_ + h)*DKV_ + R_ + i]      = (q1*cs - q2*sn)*SC;
    qfull[((size_t)b*H_ + h)*DKV_ + R_ + 32 + i] = (q2*cs + q1*sn)*SC;
  }
}

// ---------------- ql = q_nope @ W_K[h]^T, scaled, written into qfull[:, :, 0:512] ----------------
__global__ __launch_bounds__(256) void ql_gemm(const float* __restrict__ qn,
    const float* __restrict__ WK, const float* __restrict__ WKs, float* __restrict__ qfull) {
  __shared__ float As[64*132];
  __shared__ float Bs[64*132];
  const int h = blockIdx.x, rt = blockIdx.y, t = threadIdx.x;
  #pragma unroll
  for (int l=0;l<8;l++) {
    int idx = t + l*256;
    int row = idx >> 5, c4 = idx & 31;
    *reinterpret_cast<float4*>(&As[row*132 + c4*4]) = ld4(&qn[((size_t)row*H_ + h)*NOPE_ + c4*4]);
    *reinterpret_cast<float4*>(&Bs[row*132 + c4*4]) = ld4(&WK[((size_t)h*R_ + rt*64 + row)*NOPE_ + c4*4]);
  }
  __syncthreads();
  const int tb = t & 15, tr2 = t >> 4;
  float acc[4][4] = {};
  for (int k=0;k<NOPE_;k++) {
    float a[4], bb[4];
    #pragma unroll
    for (int i=0;i<4;i++) a[i] = As[(tb+16*i)*132 + k];
    #pragma unroll
    for (int j=0;j<4;j++) bb[j] = Bs[(tr2+16*j)*132 + k];
    #pragma unroll
    for (int i=0;i<4;i++)
      #pragma unroll
      for (int j=0;j<4;j++) acc[i][j] += a[i]*bb[j];
  }
  const float sc = WKs[0] * 0.0721687836487032f;
  #pragma unroll
  for (int i=0;i<4;i++)
    #pragma unroll
    for (int j=0;j<4;j++) {
      int b = tb+16*i, r = rt*64 + tr2 + 16*j;
      qfull[((size_t)b*H_ + h)*DKV_ + r] = acc[i][j]*sc;
    }
}

// ---------------- flash-decode attention chunk: full-MFMA, tr-read PV, async-staged gather ----
// krows layout: [dgrp=d/16][key=16][dsub=16] shorts, dgrp stride DGSTR_=264, double-buffered.
// Scores (16x16x32): A[key][d] b128 from krows, B=Q regs. D: col=lane&15=head, row=(lane>>4)*4+reg=key.
// PV (32x32x16): A[m=r(l31)][k=key(hi*8+j)] via ds_read_b64_tr_b16 (input lane i elem e ->
//   output lane (i&3)*4+e elem i>>2), B=P bf16 LDS. 2 raw barriers/iter, vmcnt left
//   outstanding across barriers (T4); gather split issue-early/write-late (T14).
__global__ __launch_bounds__(256) void attn_chunk(const float* __restrict__ qfull,
    const float* __restrict__ kv, const int* __restrict__ topk,
    float* __restrict__ om, float* __restrict__ ol, float* __restrict__ op) {
  __shared__ __align__(16) short krows[2][KRSZ_];     // 2 x 19,008 B
  __shared__ __align__(16) short P_lds[H_*VTS_];      // 1,536 B
  __shared__ float Spart[2*16*33];                    // 4,224 B
  __shared__ float fl[H_];
  __shared__ int tk_lds[CHUNK_];
  const int kc = blockIdx.x, b = blockIdx.y, t = threadIdx.x;
  const int lane = t & 63, wid = t >> 6;
  const int wm = wid >> 1, dn = wid & 1;   // score role: head-block, d-half
  const int lk = lane & 15, lg = lane >> 4;
  const int l31 = lane & 31, hi = lane >> 5;
  const int h16 = wm*16 + lk;

  // hoist Q fragments: head h16, d = dn*288 + ks*32 + lg*8
  bf16x8 qf[9];
  {
    const float* qb = &qfull[((size_t)b*H_ + h16)*DKV_ + dn*288 + lg*8];
    #pragma unroll
    for (int ks=0; ks<9; ++ks) {
      float4 u = ld4(qb + ks*32);
      float4 v = ld4(qb + ks*32 + 4);
      bf16x8 f;
      f[0]=f2b(u.x); f[1]=f2b(u.y); f[2]=f2b(u.z); f[3]=f2b(u.w);
      f[4]=f2b(v.x); f[5]=f2b(v.y); f[6]=f2b(v.z); f[7]=f2b(v.w);
      qf[ks] = f;
    }
  }

  // gather decomposition (thread-const, fully unrolled -> registers)
  int row_l[9], coff_l[9], woff_l[9];
  #pragma unroll
  for (int l=0;l<9;l++) {
    int idx = t + l*256;                 // 16*144 = 2304 = 9*256
    int row = idx/144, c = idx - row*144;
    int d0 = c*4;
    row_l[l] = row; coff_l[l] = d0;
    woff_l[l] = (d0>>4)*DGSTR_ + row*16 + (d0&15);
  }
  const float* kvb = kv + (size_t)b*S_*DKV_;
  const int kbase = b*TOPK_ + kc*CHUNK_;
  tk_lds[t] = topk[kbase + t];
  __syncthreads();

  float4 st[9];
  #define ISSUE(G) { \
    _Pragma("unroll") \
    for (int l=0;l<9;l++) { \
      int ki = tk_lds[(G)*TILE_ + row_l[l]]; \
      st[l] = ld4(kvb + (size_t)ki*DKV_ + coff_l[l]); \
    } }
  #define WBUF(KB) { \
    _Pragma("unroll") \
    for (int l=0;l<9;l++) { \
      short4 s4; s4.x=f2b(st[l].x); s4.y=f2b(st[l].y); s4.z=f2b(st[l].z); s4.w=f2b(st[l].w); \
      *reinterpret_cast<short4*>(&(KB)[woff_l[l]]) = s4; \
    } }

  ISSUE(0);
  WBUF(krows[0]);
  ISSUE(1);
  asm volatile("s_waitcnt lgkmcnt(0)\n\ts_barrier" ::: "memory");

  float m_run = -INFINITY, l_run = 0.f;
  f32x16 acc[4];
  #pragma unroll
  for (int tt=0;tt<4;tt++)
    #pragma unroll
    for (int i=0;i<16;i++) acc[tt][i] = 0.f;

  const int soff = (dn*18 + (lg>>1))*DGSTR_ + lk*16 + (lg&1)*8;
  const int i15 = lk;
  const unsigned trc = (unsigned)((((wid*8) + ((lane>>4)&1))*DGSTR_ + (hi*8 + (i15>>2))*16 + (i15&3)*4)*2);

  for (int g=0; g<NG_; ++g) {
    const int cur = g & 1;
    short* kb = krows[cur];
    // ---- phase A: scores ----
    f32x4 sacc = {0.f,0.f,0.f,0.f};
    #pragma unroll
    for (int ks=0; ks<9; ++ks) {
      bf16x8 af = *reinterpret_cast<const bf16x8*>(&kb[soff + ks*(2*DGSTR_)]);
      sacc = __builtin_amdgcn_mfma_f32_16x16x32_bf16(af, qf[ks], sacc, 0, 0, 0);
    }
    #pragma unroll
    for (int r=0;r<4;r++)
      Spart[dn*528 + (lg*4+r)*33 + h16] = sacc[r];
    asm volatile("s_waitcnt lgkmcnt(0)\n\ts_barrier" ::: "memory");

    // ---- phase B: softmax + P/fl write + staged LDS write (tile g+1) + issue (tile g+2) ----
    float sfull[4];
    #pragma unroll
    for (int r=0;r<4;r++)
      sfull[r] = Spart[(lg*4+r)*33 + h16] + Spart[528 + (lg*4+r)*33 + h16];
    float tmax = fmaxf(fmaxf(sfull[0],sfull[1]), fmaxf(sfull[2],sfull[3]));
    tmax = fmaxf(tmax, __shfl_xor(tmax, 16));
    tmax = fmaxf(tmax, __shfl_xor(tmax, 32));
    float m_new = fmaxf(m_run, tmax);
    float fscale = __expf(m_run - m_new);
    m_run = m_new;
    float p0 = __expf(sfull[0]-m_new), p1 = __expf(sfull[1]-m_new);
    float p2 = __expf(sfull[2]-m_new), p3 = __expf(sfull[3]-m_new);
    float ps = (p0+p1)+(p2+p3);
    ps += __shfl_xor(ps, 16);
    ps += __shfl_xor(ps, 32);
    l_run = l_run*fscale + ps;
    if (dn==0) {
      short4 pk; pk.x=f2b(p0); pk.y=f2b(p1); pk.z=f2b(p2); pk.w=f2b(p3);
      *reinterpret_cast<short4*>(&P_lds[h16*VTS_ + lg*4]) = pk;
      if (lg==0) fl[h16] = fscale;
    }
    if (g < NG_-1) WBUF(krows[cur^1]);
    if (g < NG_-2) ISSUE(g+2);
    asm volatile("s_waitcnt lgkmcnt(0)\n\ts_barrier" ::: "memory");

    // ---- phase C: PV via tr-read + 32x32x16 MFMA ----
    float fsc = fl[l31];
    bf16x8 pf = *reinterpret_cast<const bf16x8*>(&P_lds[l31*VTS_ + hi*8]);
    unsigned kaddr = (unsigned)(unsigned long long)(void*)kb;
    s16x4 tr0_0 = tr_read(kaddr + trc + 0*1056);
    s16x4 tr1_0 = tr_read(kaddr + trc + 0*1056 + 128);
    s16x4 tr0_1 = tr_read(kaddr + trc + 1*1056);
    s16x4 tr1_1 = tr_read(kaddr + trc + 1*1056 + 128);
    s16x4 tr0_2 = tr_read(kaddr + trc + 2*1056);
    s16x4 tr1_2 = tr_read(kaddr + trc + 2*1056 + 128);
    s16x4 tr0_3 = tr_read(kaddr + trc + 3*1056);
    s16x4 tr1_3 = tr_read(kaddr + trc + 3*1056 + 128);
    #pragma unroll
    for (int tt=0;tt<4;tt++)
      #pragma unroll
      for (int i=0;i<16;i++) acc[tt][i] *= fsc;
    asm volatile("s_waitcnt lgkmcnt(0)" ::: "memory");
    __builtin_amdgcn_sched_barrier(0);
    {
      bf16x8 vf;
      vf[0]=tr0_0[0]; vf[1]=tr0_0[1]; vf[2]=tr0_0[2]; vf[3]=tr0_0[3];
      vf[4]=tr1_0[0]; vf[5]=tr1_0[1]; vf[6]=tr1_0[2]; vf[7]=tr1_0[3];
      acc[0] = __builtin_amdgcn_mfma_f32_32x32x16_bf16(vf, pf, acc[0], 0, 0, 0);
      vf[0]=tr0_1[0]; vf[1]=tr0_1[1]; vf[2]=tr0_1[2]; vf[3]=tr0_1[3];
      vf[4]=tr1_1[0]; vf[5]=tr1_1[1]; vf[6]=tr1_1[2]; vf[7]=tr1_1[3];
      acc[1] = __builtin_amdgcn_mfma_f32_32x32x16_bf16(vf, pf, acc[1], 0, 0, 0);
      vf[0]=tr0_2[0]; vf[1]=tr0_2[1]; vf[2]=tr0_2[2]; vf[3]=tr0_2[3];
      vf[4]=tr1_2[0]; vf[5]=tr1_2[1]; vf[6]=tr1_2[2]; vf[7]=tr1_2[3];
      acc[2] = __builtin_amdgcn_mfma_f32_32x32x16_bf16(vf, pf, acc[2], 0, 0, 0);
      vf[0]=tr0_3[0]; vf[1]=tr0_3[1]; vf[2]=tr0_3[2]; vf[3]=tr0_3[3];
      vf[4]=tr1_3[0]; vf[5]=tr1_3[1]; vf[6]=tr1_3[2]; vf[7]=tr1_3[3];
      acc[3] = __builtin_amdgcn_mfma_f32_32x32x16_bf16(vf, pf, acc[3], 0, 0, 0);
    }
    // no barrier here: next phase A touches only krows[cur^1]/Spart; phase C touched krows[cur]/P_lds/fl.
  }

  // stats
  if (dn==0 && lg==0) {
    om[(b*ACH_+kc)*H_ + h16] = m_run;
    ol[(b*ACH_+kc)*H_ + h16] = l_run;
  }
  // o write: lane holds head h=l31, rows r = wid*128 + tt*32 + 8q + 4*hi + (0..3)
  #pragma unroll
  for (int tt=0;tt<4;tt++)
    #pragma unroll
    for (int q=0;q<4;q++) {
      float4 v = make_float4(acc[tt][4*q+0], acc[tt][4*q+1], acc[tt][4*q+2], acc[tt][4*q+3]);
      int r0 = wid*128 + tt*32 + 8*q + 4*hi;
      *reinterpret_cast<float4*>(&op[(((size_t)(b*ACH_+kc))*H_ + l31)*R_ + r0]) = v;
    }
  #undef ISSUE
  #undef WBUF
}

// ---------------- merge chunk partials ----------------
__global__ __launch_bounds__(128) void attn_merge(const float* __restrict__ om,
    const float* __restrict__ ol, const float* __restrict__ op, float* __restrict__ obuf) {
  const int bh = blockIdx.x;
  const int b = bh >> 5, h = bh & 31;
  const int t = threadIdx.x;
  float mv[8], lv[8], w[8];
  float M = -INFINITY;
  #pragma unroll
  for (int c=0;c<8;c++) { mv[c] = om[(b*ACH_+c)*H_ + h]; lv[c] = ol[(b*ACH_+c)*H_+h]; M = fmaxf(M, mv[c]); }
  float L = 0.f;
  #pragma unroll
  for (int c=0;c<8;c++) { w[c] = __expf(mv[c]-M); L += lv[c]*w[c]; }
  float inv = 1.0f / L;
  float4 s = make_float4(0.f,0.f,0.f,0.f);
  #pragma unroll
  for (int c=0;c<8;c++) {
    float4 v = ld4(&op[(((size_t)(b*ACH_+c))*H_ + h)*R_ + t*4]);
    s.x += v.x*w[c]; s.y += v.y*w[c]; s.z += v.z*w[c]; s.w += v.w*w[c];
  }
  s.x*=inv; s.y*=inv; s.z*=inv; s.w*=inv;
  *reinterpret_cast<float4*>(&obuf[((size_t)b*H_+h)*R_ + t*4]) = s;
}

// ---------------- out = o @ W_V[h]^T * scale ----------------
__global__ __launch_bounds__(256) void vproj(const float* __restrict__ obuf,
    const float* __restrict__ WV, const float* __restrict__ WVs, float* __restrict__ mid) {
  __shared__ float As[64*68];
  __shared__ float Bs[64*68];
  const int h = blockIdx.x, vt = blockIdx.y, t = threadIdx.x;
  const int tb = t & 15, tr2 = t >> 4;
  float acc[4][4] = {};
  for (int k0=0;k0<R_;k0+=64) {
    #pragma unroll
    for (int l=0;l<4;l++) {
      int idx = t + l*256;
      int row = idx >> 4, c4 = idx & 15;
      *reinterpret_cast<float4*>(&As[row*68 + c4*4]) = ld4(&obuf[((size_t)row*H_+h)*R_ + k0 + c4*4]);
      *reinterpret_cast<float4*>(&Bs[row*68 + c4*4]) = ld4(&WV[((size_t)h*V_ + vt*64 + row)*R_ + k0 + c4*4]);
    }
    __syncthreads();
    #pragma unroll
    for (int k=0;k<64;k++) {
      float a[4], bb[4];
      #pragma unroll
      for (int i=0;i<4;i++) a[i] = As[(tb+16*i)*68 + k];
      #pragma unroll
      for (int j=0;j<4;j++) bb[j] = Bs[(tr2+16*j)*68 + k];
      #pragma unroll
      for (int i=0;i<4;i++)
        #pragma unroll
        for (int j=0;j<4;j++) acc[i][j] += a[i]*bb[j];
    }
    __syncthreads();
  }
  const float sc = WVs[0];
  #pragma unroll
  for (int i=0;i<4;i++)
    #pragma unroll
    for (int j=0;j<4;j++)
      mid[(size_t)(tb+16*i)*HID_ + h*V_ + vt*64 + tr2 + 16*j] = acc[i][j]*sc;
}

// ---------------- final reduce of Wo partials ----------------
__global__ __launch_bounds__(256) void reduce_out(const float* __restrict__ op2, float* __restrict__ out) {
  int idx = blockIdx.x*256 + threadIdx.x; // float4 index
  float4 s = make_float4(0.f,0.f,0.f,0.f);
  #pragma unroll
  for (int c=0;c<KCH_;c++) {
    float4 v = ld4(&op2[(size_t)c*B_*HID_ + (size_t)idx*4]);
    s.x+=v.x; s.y+=v.y; s.z+=v.z; s.w+=v.w;
  }
  *reinterpret_cast<float4*>(&out[(size_t)idx*4]) = s;
}

extern "C" void kernel_launch(void* const* d_in, const int* in_sizes, int n_in,
                              void* d_out, int out_size, void* d_ws, size_t ws_size,
                              hipStream_t stream) {
  (void)in_sizes; (void)n_in; (void)out_size; (void)ws_size;
  const float* x   = (const float*)d_in[0];
  const float* Wq  = (const float*)d_in[1];
  const float* WK  = (const float*)d_in[2];
  const float* WKs = (const float*)d_in[3];
  const float* WV  = (const float*)d_in[4];
  const float* WVs = (const float*)d_in[5];
  const float* Wo  = (const float*)d_in[6];
  const float* kv  = (const float*)d_in[7];
  const int* topk  = (const int*)d_in[8];
  const int* pos   = (const int*)d_in[9];
  float* ws = (float*)d_ws;
  float* qp    = ws;                                   // 8*64*6144    = 3,145,728
  float* qn    = qp    + (size_t)8*64*6144;            // 64*32*128    =   262,144
  float* qfull = qn    + (size_t)64*32*128;            // 64*32*576    = 1,179,648
  float* om    = qfull + (size_t)64*32*576;            // 64*8*32
  float* ol    = om    + (size_t)64*8*32;              // 64*8*32
  float* op    = ol    + (size_t)64*8*32;              // 64*8*32*512  = 8,388,608
  float* obuf  = op    + (size_t)64*8*32*512;          // 64*32*512    = 1,048,576
  float* mid   = obuf  + (size_t)64*32*512;            // 64*4096      =   262,144
  float* op2   = mid   + (size_t)64*4096;              // 8*64*4096    = 2,097,152
  float* outf  = (float*)d_out;

  gemm64_partial<<<dim3(48,8),256,0,stream>>>(x, Wq, qp, NQ_, HID_);
  reduce_rope<<<64,256,0,stream>>>(qp, pos, qn, qfull);
  ql_gemm<<<dim3(32,8),256,0,stream>>>(qn, WK, WKs, qfull);
  attn_chunk<<<dim3(8,64),256,0,stream>>>(qfull, kv, topk, om, ol, op);
  attn_merge<<<2048,128,0,stream>>>(om, ol, op, obuf);
  vproj<<<dim3(32,2),256,0,stream>>>(obuf, WV, WVs, mid);
  gemm64_partial<<<dim3(32,8),256,0,stream>>>(mid, Wo, op2, HID_, HID_);
  reduce_out<<<256,256,0,stream>>>(op2, outf);
}

// Round 9
// 213.347 us; speedup vs baseline: 23.7206x; 1.1180x over previous
//
#include <hip/hip_runtime.h>
#include <hip/hip_bf16.h>
#include <math.h>

#define H_ 32
#define R_ 512
#define NOPE_ 128
#define ROPE_ 64
#define V_ 128
#define HID_ 4096
#define B_ 64
#define S_ 4096
#define TOPK_ 2048
#define DQ_ 192      // NOPE+ROPE
#define NQ_ 6144     // H*DQ
#define DKV_ 576     // R+ROPE
#define KCH_ 8       // K-chunks for partial skinny GEMMs
#define ACH_ 8       // attention k-chunks
#define CHUNK_ 256   // TOPK/ACH
#define TILE_ 16     // gathered rows per inner iteration
#define NG_ (CHUNK_/TILE_)   // 16 inner iterations
#define DGSTR_ 264   // krows dgrp stride in shorts (16key*16d = 256 + 8 pad)
#define KRSZ_ (36*DGSTR_)    // shorts per buffer
#define VTS_ 24      // P_lds stride (shorts)

typedef __attribute__((ext_vector_type(8))) short bf16x8;
typedef __attribute__((ext_vector_type(4))) short s16x4;
typedef __attribute__((ext_vector_type(4))) float f32x4;
typedef __attribute__((ext_vector_type(16))) float f32x16;

__device__ __forceinline__ float4 ld4(const float* p) { return *reinterpret_cast<const float4*>(p); }
__device__ __forceinline__ short f2b(float f) {
  __hip_bfloat16 h = __float2bfloat16(f);
  short s; __builtin_memcpy(&s, &h, 2); return s;
}
__device__ __forceinline__ float b2f(short s) {
  union { unsigned u; float f; } x; x.u = ((unsigned)(unsigned short)s) << 16; return x.f;
}
__device__ __forceinline__ void split2(float v, short& h, short& l) {
  short hh = f2b(v);
  h = hh; l = f2b(v - b2f(hh));
}
__device__ __forceinline__ s16x4 tr_read(unsigned byte_addr) {
  s16x4 r;
  asm volatile("ds_read_b64_tr_b16 %0, %1" : "=v"(r) : "v"(byte_addr));
  return r;
}

// ---------------- skinny partial GEMM via MFMA bf16x3 (f32-class precision) ----------------
// C_partial[kc] (64 x N-tile 128) = A(64 x Kc) @ B(Kc x N); split w=wh+wl, x=xh+xl;
// D = xh*wh + xh*wl + xl*wh. B^T fragments built by LDS transpose (k-fast scalar writes).
__global__ __launch_bounds__(256) void gemm64_mfma(const float* __restrict__ A,
    const float* __restrict__ Bm, float* __restrict__ Cp, int N, int K) {
  __shared__ __align__(16) short Ah[64*40], Al[64*40];   // [m][k32] stride 40
  __shared__ __align__(16) float Bs[32*132];             // natural [k][n] f32
  __shared__ __align__(16) short Bh[128*40], Bl[128*40]; // [n][k32] stride 40
  const int t = threadIdx.x;
  const int nt = blockIdx.x, kc = blockIdx.y;
  const int n0 = nt*128;
  const int kchunk = K / KCH_, kbeg = kc*kchunk;
  const int lane = t & 63, wid = t >> 6;
  const int lk = lane & 15, lg = lane >> 4;
  const int wm2 = wid >> 1, wn2 = wid & 1;   // m-half(32), n-half(64)
  f32x4 acc[2][4];
  #pragma unroll
  for (int mi=0;mi<2;mi++)
    #pragma unroll
    for (int nj=0;nj<4;nj++) acc[mi][nj] = (f32x4){0.f,0.f,0.f,0.f};

  for (int k0 = kbeg; k0 < kbeg + kchunk; k0 += 32) {
    // stage A (64x32): split to Ah/Al
    #pragma unroll
    for (int l=0;l<2;l++) {
      int idx = t + l*256;
      int m = idx >> 3, kq = idx & 7;
      float4 v = ld4(&A[(size_t)m*K + k0 + kq*4]);
      short4 h4, l4;
      split2(v.x, h4.x, l4.x); split2(v.y, h4.y, l4.y);
      split2(v.z, h4.z, l4.z); split2(v.w, h4.w, l4.w);
      *reinterpret_cast<short4*>(&Ah[m*40 + kq*4]) = h4;
      *reinterpret_cast<short4*>(&Al[m*40 + kq*4]) = l4;
    }
    // stage B natural (32x128) f32
    #pragma unroll
    for (int l=0;l<4;l++) {
      int idx = t + l*256;
      int kr = idx >> 5, nq = idx & 31;
      *reinterpret_cast<float4*>(&Bs[kr*132 + nq*4]) = ld4(&Bm[(size_t)(k0+kr)*N + n0 + nq*4]);
    }
    __syncthreads();
    // transpose+split Bs -> Bh/Bl: kk fast per lane -> conflict-free writes
    #pragma unroll
    for (int l=0;l<4;l++) {
      int idx = t + l*256;
      int kk = idx & 31, ng = idx >> 5;
      float4 v = *reinterpret_cast<const float4*>(&Bs[kk*132 + ng*4]);
      short h0,l0,h1,l1,h2,l2,h3,l3;
      split2(v.x,h0,l0); split2(v.y,h1,l1); split2(v.z,h2,l2); split2(v.w,h3,l3);
      Bh[(ng*4+0)*40 + kk] = h0; Bl[(ng*4+0)*40 + kk] = l0;
      Bh[(ng*4+1)*40 + kk] = h1; Bl[(ng*4+1)*40 + kk] = l1;
      Bh[(ng*4+2)*40 + kk] = h2; Bl[(ng*4+2)*40 + kk] = l2;
      Bh[(ng*4+3)*40 + kk] = h3; Bl[(ng*4+3)*40 + kk] = l3;
    }
    __syncthreads();
    // MFMA: 2 m-tiles x 4 n-tiles, 3 products each
    bf16x8 ah[2], al[2], bh[4], bl[4];
    #pragma unroll
    for (int mi=0;mi<2;mi++) {
      ah[mi] = *reinterpret_cast<const bf16x8*>(&Ah[(wm2*32+mi*16+lk)*40 + lg*8]);
      al[mi] = *reinterpret_cast<const bf16x8*>(&Al[(wm2*32+mi*16+lk)*40 + lg*8]);
    }
    #pragma unroll
    for (int nj=0;nj<4;nj++) {
      bh[nj] = *reinterpret_cast<const bf16x8*>(&Bh[(wn2*64+nj*16+lk)*40 + lg*8]);
      bl[nj] = *reinterpret_cast<const bf16x8*>(&Bl[(wn2*64+nj*16+lk)*40 + lg*8]);
    }
    #pragma unroll
    for (int mi=0;mi<2;mi++)
      #pragma unroll
      for (int nj=0;nj<4;nj++) {
        acc[mi][nj] = __builtin_amdgcn_mfma_f32_16x16x32_bf16(ah[mi], bh[nj], acc[mi][nj], 0, 0, 0);
        acc[mi][nj] = __builtin_amdgcn_mfma_f32_16x16x32_bf16(ah[mi], bl[nj], acc[mi][nj], 0, 0, 0);
        acc[mi][nj] = __builtin_amdgcn_mfma_f32_16x16x32_bf16(al[mi], bh[nj], acc[mi][nj], 0, 0, 0);
      }
    __syncthreads();
  }
  // epilogue: D row = lg*4+r, col = lk (verified m89 map)
  #pragma unroll
  for (int mi=0;mi<2;mi++)
    #pragma unroll
    for (int nj=0;nj<4;nj++)
      #pragma unroll
      for (int r=0;r<4;r++)
        Cp[((size_t)kc*64 + wm2*32 + mi*16 + lg*4 + r)*N + n0 + wn2*64 + nj*16 + lk] = acc[mi][nj][r];
}

// ---------------- reduce q partials + split nope/pe + rope ----------------
__global__ __launch_bounds__(256) void reduce_rope(const float* __restrict__ qp,
    const int* __restrict__ positions, float* __restrict__ qn, float* __restrict__ qfull) {
  __shared__ float pe[H_*ROPE_];
  const int b = blockIdx.x, t = threadIdx.x;
  for (int n = t*4; n < NQ_; n += 1024) {
    float4 s = make_float4(0.f,0.f,0.f,0.f);
    for (int c=0;c<KCH_;c++) {
      float4 v = ld4(&qp[((size_t)c*64 + b)*NQ_ + n]);
      s.x+=v.x; s.y+=v.y; s.z+=v.z; s.w+=v.w;
    }
    float vs[4] = {s.x,s.y,s.z,s.w};
    #pragma unroll
    for (int e=0;e<4;e++) {
      int nn = n+e; int h = nn/DQ_; int d = nn - h*DQ_;
      if (d < NOPE_) qn[((size_t)b*H_ + h)*NOPE_ + d] = vs[e];
      else pe[h*ROPE_ + (d-NOPE_)] = vs[e];
    }
  }
  __syncthreads();
  const float pos = (float)positions[b];
  const float SC = 0.0721687836487032f; // 1/sqrt(192)
  for (int it = t; it < H_*32; it += 256) {
    int h = it >> 5, i = it & 31;
    float invf = (float)exp(-(double)i * 0.28782313662425574); // 10000^(-i/32)
    float fr = pos * invf;
    float cs = cosf(fr), sn = sinf(fr);
    float q1 = pe[h*ROPE_ + i], q2 = pe[h*ROPE_ + 32 + i];
    qfull[((size_t)b*H_ + h)*DKV_ + R_ + i]      = (q1*cs - q2*sn)*SC;
    qfull[((size_t)b*H_ + h)*DKV_ + R_ + 32 + i] = (q2*cs + q1*sn)*SC;
  }
}

// ---------------- ql = q_nope @ W_K[h]^T, scaled, written into qfull[:, :, 0:512] ----------------
__global__ __launch_bounds__(256) void ql_gemm(const float* __restrict__ qn,
    const float* __restrict__ WK, const float* __restrict__ WKs, float* __restrict__ qfull) {
  __shared__ float As[64*132];
  __shared__ float Bs[64*132];
  const int h = blockIdx.x, rt = blockIdx.y, t = threadIdx.x;
  #pragma unroll
  for (int l=0;l<8;l++) {
    int idx = t + l*256;
    int row = idx >> 5, c4 = idx & 31;
    *reinterpret_cast<float4*>(&As[row*132 + c4*4]) = ld4(&qn[((size_t)row*H_ + h)*NOPE_ + c4*4]);
    *reinterpret_cast<float4*>(&Bs[row*132 + c4*4]) = ld4(&WK[((size_t)h*R_ + rt*64 + row)*NOPE_ + c4*4]);
  }
  __syncthreads();
  const int tb = t & 15, tr2 = t >> 4;
  float acc[4][4] = {};
  for (int k=0;k<NOPE_;k++) {
    float a[4], bb[4];
    #pragma unroll
    for (int i=0;i<4;i++) a[i] = As[(tb+16*i)*132 + k];
    #pragma unroll
    for (int j=0;j<4;j++) bb[j] = Bs[(tr2+16*j)*132 + k];
    #pragma unroll
    for (int i=0;i<4;i++)
      #pragma unroll
      for (int j=0;j<4;j++) acc[i][j] += a[i]*bb[j];
  }
  const float sc = WKs[0] * 0.0721687836487032f;
  #pragma unroll
  for (int i=0;i<4;i++)
    #pragma unroll
    for (int j=0;j<4;j++) {
      int b = tb+16*i, r = rt*64 + tr2 + 16*j;
      qfull[((size_t)b*H_ + h)*DKV_ + r] = acc[i][j]*sc;
    }
}

// ---------------- flash-decode attention chunk: full-MFMA, tr-read PV, 3-deep staged gather ----
__global__ __launch_bounds__(256) void attn_chunk(const float* __restrict__ qfull,
    const float* __restrict__ kv, const int* __restrict__ topk,
    float* __restrict__ om, float* __restrict__ ol, float* __restrict__ op) {
  __shared__ __align__(16) short krows[2][KRSZ_];     // 2 x 19,008 B
  __shared__ __align__(16) short P_lds[H_*VTS_];      // 1,536 B
  __shared__ float Spart[2*16*33];                    // 4,224 B
  __shared__ float fl[H_];
  __shared__ int tk_lds[CHUNK_];
  const int kc = blockIdx.x, b = blockIdx.y, t = threadIdx.x;
  const int lane = t & 63, wid = t >> 6;
  const int wm = wid >> 1, dn = wid & 1;   // score role: head-block, d-half
  const int lk = lane & 15, lg = lane >> 4;
  const int l31 = lane & 31, hi = lane >> 5;
  const int h16 = wm*16 + lk;

  // hoist Q fragments: head h16, d = dn*288 + ks*32 + lg*8
  bf16x8 qf[9];
  {
    const float* qb = &qfull[((size_t)b*H_ + h16)*DKV_ + dn*288 + lg*8];
    #pragma unroll
    for (int ks=0; ks<9; ++ks) {
      float4 u = ld4(qb + ks*32);
      float4 v = ld4(qb + ks*32 + 4);
      bf16x8 f;
      f[0]=f2b(u.x); f[1]=f2b(u.y); f[2]=f2b(u.z); f[3]=f2b(u.w);
      f[4]=f2b(v.x); f[5]=f2b(v.y); f[6]=f2b(v.z); f[7]=f2b(v.w);
      qf[ks] = f;
    }
  }

  // gather decomposition (thread-const)
  int row_l[9], coff_l[9], woff_l[9];
  #pragma unroll
  for (int l=0;l<9;l++) {
    int idx = t + l*256;                 // 16*144 = 2304 = 9*256
    int row = idx/144, c = idx - row*144;
    int d0 = c*4;
    row_l[l] = row; coff_l[l] = d0;
    woff_l[l] = (d0>>4)*DGSTR_ + row*16 + (d0&15);
  }
  const float* kvb = kv + (size_t)b*S_*DKV_;
  const int kbase = b*TOPK_ + kc*CHUNK_;
  tk_lds[t] = topk[kbase + t];
  __syncthreads();

  float4 stA[9], stB[9];
  #define ISSUE(ST, G) { \
    _Pragma("unroll") \
    for (int l=0;l<9;l++) { \
      int ki = tk_lds[(G)*TILE_ + row_l[l]]; \
      ST[l] = ld4(kvb + (size_t)ki*DKV_ + coff_l[l]); \
    } }
  #define WBUF(KB, ST) { \
    _Pragma("unroll") \
    for (int l=0;l<9;l++) { \
      short4 s4; s4.x=f2b(ST[l].x); s4.y=f2b(ST[l].y); s4.z=f2b(ST[l].z); s4.w=f2b(ST[l].w); \
      *reinterpret_cast<short4*>(&(KB)[woff_l[l]]) = s4; \
    } }

  // prologue: kr0 <- tile0; stA <- tile1; stB <- tile2 (3-deep)
  ISSUE(stA, 0);
  WBUF(krows[0], stA);
  ISSUE(stA, 1);
  ISSUE(stB, 2);
  asm volatile("s_waitcnt lgkmcnt(0)\n\ts_barrier" ::: "memory");

  float m_run = -INFINITY, l_run = 0.f;
  f32x16 acc[4];
  #pragma unroll
  for (int tt=0;tt<4;tt++)
    #pragma unroll
    for (int i=0;i<16;i++) acc[tt][i] = 0.f;

  const int soff = (dn*18 + (lg>>1))*DGSTR_ + lk*16 + (lg&1)*8;
  const int i15 = lk;
  const unsigned trc = (unsigned)((((wid*8) + ((lane>>4)&1))*DGSTR_ + (hi*8 + (i15>>2))*16 + (i15&3)*4)*2);

  for (int g=0; g<NG_; ++g) {
    const int cur = g & 1;
    short* kb = krows[cur];
    // ---- phase A: scores ----
    f32x4 sacc = {0.f,0.f,0.f,0.f};
    #pragma unroll
    for (int ks=0; ks<9; ++ks) {
      bf16x8 af = *reinterpret_cast<const bf16x8*>(&kb[soff + ks*(2*DGSTR_)]);
      sacc = __builtin_amdgcn_mfma_f32_16x16x32_bf16(af, qf[ks], sacc, 0, 0, 0);
    }
    #pragma unroll
    for (int r=0;r<4;r++)
      Spart[dn*528 + (lg*4+r)*33 + h16] = sacc[r];
    asm volatile("s_waitcnt lgkmcnt(0)\n\ts_barrier" ::: "memory");

    // ---- phase B: softmax + P/fl write + staged LDS write (tile g+1) + issue (tile g+3) ----
    float sfull[4];
    #pragma unroll
    for (int r=0;r<4;r++)
      sfull[r] = Spart[(lg*4+r)*33 + h16] + Spart[528 + (lg*4+r)*33 + h16];
    float tmax = fmaxf(fmaxf(sfull[0],sfull[1]), fmaxf(sfull[2],sfull[3]));
    tmax = fmaxf(tmax, __shfl_xor(tmax, 16));
    tmax = fmaxf(tmax, __shfl_xor(tmax, 32));
    float m_new = fmaxf(m_run, tmax);
    float fscale = __expf(m_run - m_new);
    m_run = m_new;
    float p0 = __expf(sfull[0]-m_new), p1 = __expf(sfull[1]-m_new);
    float p2 = __expf(sfull[2]-m_new), p3 = __expf(sfull[3]-m_new);
    float ps = (p0+p1)+(p2+p3);
    ps += __shfl_xor(ps, 16);
    ps += __shfl_xor(ps, 32);
    l_run = l_run*fscale + ps;
    if (dn==0) {
      short4 pk; pk.x=f2b(p0); pk.y=f2b(p1); pk.z=f2b(p2); pk.w=f2b(p3);
      *reinterpret_cast<short4*>(&P_lds[h16*VTS_ + lg*4]) = pk;
      if (lg==0) fl[h16] = fscale;
    }
    // tile t consumed at g=t-1, issued at g=t-3; parity of set matches g
    if ((g & 1) == 0) {
      if (g < NG_-1) WBUF(krows[cur^1], stA);
      if (g+3 < NG_) ISSUE(stA, g+3);
    } else {
      if (g < NG_-1) WBUF(krows[cur^1], stB);
      if (g+3 < NG_) ISSUE(stB, g+3);
    }
    asm volatile("s_waitcnt lgkmcnt(0)\n\ts_barrier" ::: "memory");

    // ---- phase C: PV via tr-read + 32x32x16 MFMA ----
    float fsc = fl[l31];
    bf16x8 pf = *reinterpret_cast<const bf16x8*>(&P_lds[l31*VTS_ + hi*8]);
    unsigned kaddr = (unsigned)(unsigned long long)(void*)kb;
    s16x4 tr0_0 = tr_read(kaddr + trc + 0*1056);
    s16x4 tr1_0 = tr_read(kaddr + trc + 0*1056 + 128);
    s16x4 tr0_1 = tr_read(kaddr + trc + 1*1056);
    s16x4 tr1_1 = tr_read(kaddr + trc + 1*1056 + 128);
    s16x4 tr0_2 = tr_read(kaddr + trc + 2*1056);
    s16x4 tr1_2 = tr_read(kaddr + trc + 2*1056 + 128);
    s16x4 tr0_3 = tr_read(kaddr + trc + 3*1056);
    s16x4 tr1_3 = tr_read(kaddr + trc + 3*1056 + 128);
    #pragma unroll
    for (int tt=0;tt<4;tt++)
      #pragma unroll
      for (int i=0;i<16;i++) acc[tt][i] *= fsc;
    asm volatile("s_waitcnt lgkmcnt(0)" ::: "memory");
    __builtin_amdgcn_sched_barrier(0);
    {
      bf16x8 vf;
      vf[0]=tr0_0[0]; vf[1]=tr0_0[1]; vf[2]=tr0_0[2]; vf[3]=tr0_0[3];
      vf[4]=tr1_0[0]; vf[5]=tr1_0[1]; vf[6]=tr1_0[2]; vf[7]=tr1_0[3];
      acc[0] = __builtin_amdgcn_mfma_f32_32x32x16_bf16(vf, pf, acc[0], 0, 0, 0);
      vf[0]=tr0_1[0]; vf[1]=tr0_1[1]; vf[2]=tr0_1[2]; vf[3]=tr0_1[3];
      vf[4]=tr1_1[0]; vf[5]=tr1_1[1]; vf[6]=tr1_1[2]; vf[7]=tr1_1[3];
      acc[1] = __builtin_amdgcn_mfma_f32_32x32x16_bf16(vf, pf, acc[1], 0, 0, 0);
      vf[0]=tr0_2[0]; vf[1]=tr0_2[1]; vf[2]=tr0_2[2]; vf[3]=tr0_2[3];
      vf[4]=tr1_2[0]; vf[5]=tr1_2[1]; vf[6]=tr1_2[2]; vf[7]=tr1_2[3];
      acc[2] = __builtin_amdgcn_mfma_f32_32x32x16_bf16(vf, pf, acc[2], 0, 0, 0);
      vf[0]=tr0_3[0]; vf[1]=tr0_3[1]; vf[2]=tr0_3[2]; vf[3]=tr0_3[3];
      vf[4]=tr1_3[0]; vf[5]=tr1_3[1]; vf[6]=tr1_3[2]; vf[7]=tr1_3[3];
      acc[3] = __builtin_amdgcn_mfma_f32_32x32x16_bf16(vf, pf, acc[3], 0, 0, 0);
    }
    // no barrier here: next phase A touches only krows[cur^1]/Spart.
  }

  if (dn==0 && lg==0) {
    om[(b*ACH_+kc)*H_ + h16] = m_run;
    ol[(b*ACH_+kc)*H_ + h16] = l_run;
  }
  #pragma unroll
  for (int tt=0;tt<4;tt++)
    #pragma unroll
    for (int q=0;q<4;q++) {
      float4 v = make_float4(acc[tt][4*q+0], acc[tt][4*q+1], acc[tt][4*q+2], acc[tt][4*q+3]);
      int r0 = wid*128 + tt*32 + 8*q + 4*hi;
      *reinterpret_cast<float4*>(&op[(((size_t)(b*ACH_+kc))*H_ + l31)*R_ + r0]) = v;
    }
  #undef ISSUE
  #undef WBUF
}

// ---------------- merge chunk partials ----------------
__global__ __launch_bounds__(128) void attn_merge(const float* __restrict__ om,
    const float* __restrict__ ol, const float* __restrict__ op, float* __restrict__ obuf) {
  const int bh = blockIdx.x;
  const int b = bh >> 5, h = bh & 31;
  const int t = threadIdx.x;
  float mv[8], lv[8], w[8];
  float M = -INFINITY;
  #pragma unroll
  for (int c=0;c<8;c++) { mv[c] = om[(b*ACH_+c)*H_ + h]; lv[c] = ol[(b*ACH_+c)*H_+h]; M = fmaxf(M, mv[c]); }
  float L = 0.f;
  #pragma unroll
  for (int c=0;c<8;c++) { w[c] = __expf(mv[c]-M); L += lv[c]*w[c]; }
  float inv = 1.0f / L;
  float4 s = make_float4(0.f,0.f,0.f,0.f);
  #pragma unroll
  for (int c=0;c<8;c++) {
    float4 v = ld4(&op[(((size_t)(b*ACH_+c))*H_ + h)*R_ + t*4]);
    s.x += v.x*w[c]; s.y += v.y*w[c]; s.z += v.z*w[c]; s.w += v.w*w[c];
  }
  s.x*=inv; s.y*=inv; s.z*=inv; s.w*=inv;
  *reinterpret_cast<float4*>(&obuf[((size_t)b*H_+h)*R_ + t*4]) = s;
}

// ---------------- out = o @ W_V[h]^T * scale ----------------
__global__ __launch_bounds__(256) void vproj(const float* __restrict__ obuf,
    const float* __restrict__ WV, const float* __restrict__ WVs, float* __restrict__ mid) {
  __shared__ float As[64*68];
  __shared__ float Bs[64*68];
  const int h = blockIdx.x, vt = blockIdx.y, t = threadIdx.x;
  const int tb = t & 15, tr2 = t >> 4;
  float acc[4][4] = {};
  for (int k0=0;k0<R_;k0+=64) {
    #pragma unroll
    for (int l=0;l<4;l++) {
      int idx = t + l*256;
      int row = idx >> 4, c4 = idx & 15;
      *reinterpret_cast<float4*>(&As[row*68 + c4*4]) = ld4(&obuf[((size_t)row*H_+h)*R_ + k0 + c4*4]);
      *reinterpret_cast<float4*>(&Bs[row*68 + c4*4]) = ld4(&WV[((size_t)h*V_ + vt*64 + row)*R_ + k0 + c4*4]);
    }
    __syncthreads();
    #pragma unroll
    for (int k=0;k<64;k++) {
      float a[4], bb[4];
      #pragma unroll
      for (int i=0;i<4;i++) a[i] = As[(tb+16*i)*68 + k];
      #pragma unroll
      for (int j=0;j<4;j++) bb[j] = Bs[(tr2+16*j)*68 + k];
      #pragma unroll
      for (int i=0;i<4;i++)
        #pragma unroll
        for (int j=0;j<4;j++) acc[i][j] += a[i]*bb[j];
    }
    __syncthreads();
  }
  const float sc = WVs[0];
  #pragma unroll
  for (int i=0;i<4;i++)
    #pragma unroll
    for (int j=0;j<4;j++)
      mid[(size_t)(tb+16*i)*HID_ + h*V_ + vt*64 + tr2 + 16*j] = acc[i][j]*sc;
}

// ---------------- final reduce of Wo partials ----------------
__global__ __launch_bounds__(256) void reduce_out(const float* __restrict__ op2, float* __restrict__ out) {
  int idx = blockIdx.x*256 + threadIdx.x; // float4 index
  float4 s = make_float4(0.f,0.f,0.f,0.f);
  #pragma unroll
  for (int c=0;c<KCH_;c++) {
    float4 v = ld4(&op2[(size_t)c*B_*HID_ + (size_t)idx*4]);
    s.x+=v.x; s.y+=v.y; s.z+=v.z; s.w+=v.w;
  }
  *reinterpret_cast<float4*>(&out[(size_t)idx*4]) = s;
}

extern "C" void kernel_launch(void* const* d_in, const int* in_sizes, int n_in,
                              void* d_out, int out_size, void* d_ws, size_t ws_size,
                              hipStream_t stream) {
  (void)in_sizes; (void)n_in; (void)out_size; (void)ws_size;
  const float* x   = (const float*)d_in[0];
  const float* Wq  = (const float*)d_in[1];
  const float* WK  = (const float*)d_in[2];
  const float* WKs = (const float*)d_in[3];
  const float* WV  = (const float*)d_in[4];
  const float* WVs = (const float*)d_in[5];
  const float* Wo  = (const float*)d_in[6];
  const float* kv  = (const float*)d_in[7];
  const int* topk  = (const int*)d_in[8];
  const int* pos   = (const int*)d_in[9];
  float* ws = (float*)d_ws;
  float* qp    = ws;                                   // 8*64*6144    = 3,145,728
  float* qn    = qp    + (size_t)8*64*6144;            // 64*32*128    =   262,144
  float* qfull = qn    + (size_t)64*32*128;            // 64*32*576    = 1,179,648
  float* om    = qfull + (size_t)64*32*576;            // 64*8*32
  float* ol    = om    + (size_t)64*8*32;              // 64*8*32
  float* op    = ol    + (size_t)64*8*32;              // 64*8*32*512  = 8,388,608
  float* obuf  = op    + (size_t)64*8*32*512;          // 64*32*512    = 1,048,576
  float* mid   = obuf  + (size_t)64*32*512;            // 64*4096      =   262,144
  float* op2   = mid   + (size_t)64*4096;              // 8*64*4096    = 2,097,152
  float* outf  = (float*)d_out;

  gemm64_mfma<<<dim3(48,8),256,0,stream>>>(x, Wq, qp, NQ_, HID_);
  reduce_rope<<<64,256,0,stream>>>(qp, pos, qn, qfull);
  ql_gemm<<<dim3(32,8),256,0,stream>>>(qn, WK, WKs, qfull);
  attn_chunk<<<dim3(8,64),256,0,stream>>>(qfull, kv, topk, om, ol, op);
  attn_merge<<<2048,128,0,stream>>>(om, ol, op, obuf);
  vproj<<<dim3(32,2),256,0,stream>>>(obuf, WV, WVs, mid);
  gemm64_mfma<<<dim3(32,8),256,0,stream>>>(mid, Wo, op2, HID_, HID_);
  reduce_out<<<256,256,0,stream>>>(op2, outf);
}

// Round 10
// 202.089 us; speedup vs baseline: 25.0420x; 1.0557x over previous
//
#include <hip/hip_runtime.h>
#include <hip/hip_bf16.h>
#include <math.h>

#define H_ 32
#define R_ 512
#define NOPE_ 128
#define ROPE_ 64
#define V_ 128
#define HID_ 4096
#define B_ 64
#define S_ 4096
#define TOPK_ 2048
#define DQ_ 192      // NOPE+ROPE
#define NQ_ 6144     // H*DQ
#define DKV_ 576     // R+ROPE
#define KCH_ 8       // K-chunks for partial skinny GEMMs
#define ACH_ 8       // attention k-chunks
#define CHUNK_ 256   // TOPK/ACH
#define TILE_ 16     // gathered rows per inner iteration
#define NG_ (CHUNK_/TILE_)   // 16 inner iterations
#define DGSTR_ 264   // krows dgrp stride in shorts (16key*16d = 256 + 8 pad)
#define KRSZ_ (36*DGSTR_)    // shorts per buffer
#define VTS_ 24      // P_lds stride (shorts)

typedef __attribute__((ext_vector_type(8))) short bf16x8;
typedef __attribute__((ext_vector_type(4))) short s16x4;
typedef __attribute__((ext_vector_type(4))) float f32x4;
typedef __attribute__((ext_vector_type(16))) float f32x16;

__device__ __forceinline__ float4 ld4(const float* p) { return *reinterpret_cast<const float4*>(p); }
__device__ __forceinline__ short f2b(float f) {
  __hip_bfloat16 h = __float2bfloat16(f);
  short s; __builtin_memcpy(&s, &h, 2); return s;
}
__device__ __forceinline__ float b2f(short s) {
  union { unsigned u; float f; } x; x.u = ((unsigned)(unsigned short)s) << 16; return x.f;
}
__device__ __forceinline__ void split2(float v, short& h, short& l) {
  short hh = f2b(v);
  h = hh; l = f2b(v - b2f(hh));
}
__device__ __forceinline__ s16x4 tr_read(unsigned byte_addr) {
  s16x4 r;
  asm volatile("ds_read_b64_tr_b16 %0, %1" : "=v"(r) : "v"(byte_addr));
  return r;
}

// ---------------- skinny partial GEMM via MFMA bf16x3 (f32-class precision) ----------------
// C_partial[kc] (64 x N-tile 128) = (A[+A2])(64 x Kc) @ B(Kc x N); split w=wh+wl, x=xh+xl;
// D = xh*wh + xh*wl + xl*wh. B^T fragments built by LDS transpose (k-fast scalar writes).
__global__ __launch_bounds__(256) void gemm64_mfma(const float* __restrict__ A,
    const float* __restrict__ A2,
    const float* __restrict__ Bm, float* __restrict__ Cp, int N, int K) {
  __shared__ __align__(16) short Ah[64*40], Al[64*40];   // [m][k32] stride 40
  __shared__ __align__(16) float Bs[32*132];             // natural [k][n] f32
  __shared__ __align__(16) short Bh[128*40], Bl[128*40]; // [n][k32] stride 40
  const int t = threadIdx.x;
  const int nt = blockIdx.x, kc = blockIdx.y;
  const int n0 = nt*128;
  const int kchunk = K / KCH_, kbeg = kc*kchunk;
  const int lane = t & 63, wid = t >> 6;
  const int lk = lane & 15, lg = lane >> 4;
  const int wm2 = wid >> 1, wn2 = wid & 1;   // m-half(32), n-half(64)
  f32x4 acc[2][4];
  #pragma unroll
  for (int mi=0;mi<2;mi++)
    #pragma unroll
    for (int nj=0;nj<4;nj++) acc[mi][nj] = (f32x4){0.f,0.f,0.f,0.f};

  for (int k0 = kbeg; k0 < kbeg + kchunk; k0 += 32) {
    // stage A (64x32): optional A2 sum, split to Ah/Al
    #pragma unroll
    for (int l=0;l<2;l++) {
      int idx = t + l*256;
      int m = idx >> 3, kq = idx & 7;
      float4 v = ld4(&A[(size_t)m*K + k0 + kq*4]);
      if (A2) {
        float4 w = ld4(&A2[(size_t)m*K + k0 + kq*4]);
        v.x+=w.x; v.y+=w.y; v.z+=w.z; v.w+=w.w;
      }
      short4 h4, l4;
      split2(v.x, h4.x, l4.x); split2(v.y, h4.y, l4.y);
      split2(v.z, h4.z, l4.z); split2(v.w, h4.w, l4.w);
      *reinterpret_cast<short4*>(&Ah[m*40 + kq*4]) = h4;
      *reinterpret_cast<short4*>(&Al[m*40 + kq*4]) = l4;
    }
    // stage B natural (32x128) f32
    #pragma unroll
    for (int l=0;l<4;l++) {
      int idx = t + l*256;
      int kr = idx >> 5, nq = idx & 31;
      *reinterpret_cast<float4*>(&Bs[kr*132 + nq*4]) = ld4(&Bm[(size_t)(k0+kr)*N + n0 + nq*4]);
    }
    __syncthreads();
    // transpose+split Bs -> Bh/Bl: kk fast per lane -> conflict-free writes
    #pragma unroll
    for (int l=0;l<4;l++) {
      int idx = t + l*256;
      int kk = idx & 31, ng = idx >> 5;
      float4 v = *reinterpret_cast<const float4*>(&Bs[kk*132 + ng*4]);
      short h0,l0,h1,l1,h2,l2,h3,l3;
      split2(v.x,h0,l0); split2(v.y,h1,l1); split2(v.z,h2,l2); split2(v.w,h3,l3);
      Bh[(ng*4+0)*40 + kk] = h0; Bl[(ng*4+0)*40 + kk] = l0;
      Bh[(ng*4+1)*40 + kk] = h1; Bl[(ng*4+1)*40 + kk] = l1;
      Bh[(ng*4+2)*40 + kk] = h2; Bl[(ng*4+2)*40 + kk] = l2;
      Bh[(ng*4+3)*40 + kk] = h3; Bl[(ng*4+3)*40 + kk] = l3;
    }
    __syncthreads();
    // MFMA: 2 m-tiles x 4 n-tiles, 3 products each
    bf16x8 ah[2], al[2], bh[4], bl[4];
    #pragma unroll
    for (int mi=0;mi<2;mi++) {
      ah[mi] = *reinterpret_cast<const bf16x8*>(&Ah[(wm2*32+mi*16+lk)*40 + lg*8]);
      al[mi] = *reinterpret_cast<const bf16x8*>(&Al[(wm2*32+mi*16+lk)*40 + lg*8]);
    }
    #pragma unroll
    for (int nj=0;nj<4;nj++) {
      bh[nj] = *reinterpret_cast<const bf16x8*>(&Bh[(wn2*64+nj*16+lk)*40 + lg*8]);
      bl[nj] = *reinterpret_cast<const bf16x8*>(&Bl[(wn2*64+nj*16+lk)*40 + lg*8]);
    }
    #pragma unroll
    for (int mi=0;mi<2;mi++)
      #pragma unroll
      for (int nj=0;nj<4;nj++) {
        acc[mi][nj] = __builtin_amdgcn_mfma_f32_16x16x32_bf16(ah[mi], bh[nj], acc[mi][nj], 0, 0, 0);
        acc[mi][nj] = __builtin_amdgcn_mfma_f32_16x16x32_bf16(ah[mi], bl[nj], acc[mi][nj], 0, 0, 0);
        acc[mi][nj] = __builtin_amdgcn_mfma_f32_16x16x32_bf16(al[mi], bh[nj], acc[mi][nj], 0, 0, 0);
      }
    __syncthreads();
  }
  // epilogue: D row = lg*4+r, col = lk (verified m89 map)
  #pragma unroll
  for (int mi=0;mi<2;mi++)
    #pragma unroll
    for (int nj=0;nj<4;nj++)
      #pragma unroll
      for (int r=0;r<4;r++)
        Cp[((size_t)kc*64 + wm2*32 + mi*16 + lg*4 + r)*N + n0 + wn2*64 + nj*16 + lk] = acc[mi][nj][r];
}

// ---------------- M64 x N(64-tile) GEMM via MFMA: A split bf16x2, B EXACT bf16 ----------------
// For ql (B=W_K) and vproj (B=W_V): B values are fp8-quantized grid points (4 significand
// bits) stored f32 -> bf16 cast is exact. D = (ah+al)@B, 2 MFMA products = f32-class.
// A row (m=b): A + (b*H + h)*lda + kcz*nk128*128.  B row (c): Bw + h*Bhstride + (ct*64+c)*ldb + koffs.
// out elem: out + kcz*okcstride + b*ostride + h*ohstride + ct*64 + col.
__global__ __launch_bounds__(256) void gemm64x64_mfma(const float* __restrict__ A, int lda,
    const float* __restrict__ Bw, int ldb, int Bhstride,
    const float* __restrict__ scl, float smul,
    float* __restrict__ out, int ostride, int ohstride, int okcstride, int nk128) {
  __shared__ __align__(16) short Ah[64*136], Al[64*136], Bh[64*136];  // [row][k128] stride 136
  const int t = threadIdx.x;
  const int h = blockIdx.x, ct = blockIdx.y, kcz = blockIdx.z;
  const int koffs = kcz*nk128*128;
  const int lane = t & 63, wid = t >> 6;
  const int lk = lane & 15, lg = lane >> 4;
  const int wm2 = wid >> 1, wn2 = wid & 1;
  const int H = gridDim.x;
  f32x4 acc[2][2];
  #pragma unroll
  for (int mi=0;mi<2;mi++)
    #pragma unroll
    for (int nj=0;nj<2;nj++) acc[mi][nj] = (f32x4){0.f,0.f,0.f,0.f};

  for (int c=0; c<nk128; ++c) {
    if (c) __syncthreads();
    const int k0 = koffs + c*128;
    #pragma unroll
    for (int l=0;l<8;l++) {
      int idx = t + l*256;           // 64 rows x 32 quads = 2048
      int m = idx >> 5, kq = idx & 31;
      float4 v = ld4(&A[((size_t)m*H + h)*lda + k0 + kq*4]);
      short4 h4, l4;
      split2(v.x,h4.x,l4.x); split2(v.y,h4.y,l4.y);
      split2(v.z,h4.z,l4.z); split2(v.w,h4.w,l4.w);
      *reinterpret_cast<short4*>(&Ah[m*136 + kq*4]) = h4;
      *reinterpret_cast<short4*>(&Al[m*136 + kq*4]) = l4;
      float4 w = ld4(&Bw[(size_t)h*Bhstride + (size_t)(ct*64 + m)*ldb + k0 + kq*4]);
      short4 b4; b4.x=f2b(w.x); b4.y=f2b(w.y); b4.z=f2b(w.z); b4.w=f2b(w.w);  // exact
      *reinterpret_cast<short4*>(&Bh[m*136 + kq*4]) = b4;
    }
    __syncthreads();
    #pragma unroll
    for (int ks=0; ks<4; ++ks) {
      bf16x8 ah[2], al[2], bh[2];
      #pragma unroll
      for (int mi=0;mi<2;mi++) {
        ah[mi] = *reinterpret_cast<const bf16x8*>(&Ah[(wm2*32+mi*16+lk)*136 + ks*32 + lg*8]);
        al[mi] = *reinterpret_cast<const bf16x8*>(&Al[(wm2*32+mi*16+lk)*136 + ks*32 + lg*8]);
      }
      #pragma unroll
      for (int nj=0;nj<2;nj++)
        bh[nj] = *reinterpret_cast<const bf16x8*>(&Bh[(wn2*32+nj*16+lk)*136 + ks*32 + lg*8]);
      #pragma unroll
      for (int mi=0;mi<2;mi++)
        #pragma unroll
        for (int nj=0;nj<2;nj++) {
          acc[mi][nj] = __builtin_amdgcn_mfma_f32_16x16x32_bf16(ah[mi], bh[nj], acc[mi][nj], 0, 0, 0);
          acc[mi][nj] = __builtin_amdgcn_mfma_f32_16x16x32_bf16(al[mi], bh[nj], acc[mi][nj], 0, 0, 0);
        }
    }
  }
  const float sc = scl[0]*smul;
  #pragma unroll
  for (int mi=0;mi<2;mi++)
    #pragma unroll
    for (int nj=0;nj<2;nj++)
      #pragma unroll
      for (int r=0;r<4;r++) {
        int row = wm2*32 + mi*16 + lg*4 + r;
        int col = ct*64 + wn2*32 + nj*16 + lk;
        out[(size_t)kcz*okcstride + (size_t)row*ostride + (size_t)h*ohstride + col] = acc[mi][nj][r]*sc;
      }
}

// ---------------- reduce q partials + split nope/pe + rope ----------------
__global__ __launch_bounds__(256) void reduce_rope(const float* __restrict__ qp,
    const int* __restrict__ positions, float* __restrict__ qn, float* __restrict__ qfull) {
  __shared__ float pe[H_*ROPE_];
  const int b = blockIdx.x, t = threadIdx.x;
  for (int n = t*4; n < NQ_; n += 1024) {
    float4 s = make_float4(0.f,0.f,0.f,0.f);
    for (int c=0;c<KCH_;c++) {
      float4 v = ld4(&qp[((size_t)c*64 + b)*NQ_ + n]);
      s.x+=v.x; s.y+=v.y; s.z+=v.z; s.w+=v.w;
    }
    float vs[4] = {s.x,s.y,s.z,s.w};
    #pragma unroll
    for (int e=0;e<4;e++) {
      int nn = n+e; int h = nn/DQ_; int d = nn - h*DQ_;
      if (d < NOPE_) qn[((size_t)b*H_ + h)*NOPE_ + d] = vs[e];
      else pe[h*ROPE_ + (d-NOPE_)] = vs[e];
    }
  }
  __syncthreads();
  const float pos = (float)positions[b];
  const float SC = 0.0721687836487032f; // 1/sqrt(192)
  for (int it = t; it < H_*32; it += 256) {
    int h = it >> 5, i = it & 31;
    float invf = (float)exp(-(double)i * 0.28782313662425574); // 10000^(-i/32)
    float fr = pos * invf;
    float cs = cosf(fr), sn = sinf(fr);
    float q1 = pe[h*ROPE_ + i], q2 = pe[h*ROPE_ + 32 + i];
    qfull[((size_t)b*H_ + h)*DKV_ + R_ + i]      = (q1*cs - q2*sn)*SC;
    qfull[((size_t)b*H_ + h)*DKV_ + R_ + 32 + i] = (q2*cs + q1*sn)*SC;
  }
}

// ---------------- flash-decode attention chunk: full-MFMA, tr-read PV, 3-deep staged gather ----
__global__ __launch_bounds__(256) void attn_chunk(const float* __restrict__ qfull,
    const float* __restrict__ kv, const int* __restrict__ topk,
    float* __restrict__ om, float* __restrict__ ol, float* __restrict__ op) {
  __shared__ __align__(16) short krows[2][KRSZ_];     // 2 x 19,008 B
  __shared__ __align__(16) short P_lds[H_*VTS_];      // 1,536 B
  __shared__ float Spart[2*16*33];                    // 4,224 B
  __shared__ float fl[H_];
  __shared__ int tk_lds[CHUNK_];
  const int kc = blockIdx.x, b = blockIdx.y, t = threadIdx.x;
  const int lane = t & 63, wid = t >> 6;
  const int wm = wid >> 1, dn = wid & 1;   // score role: head-block, d-half
  const int lk = lane & 15, lg = lane >> 4;
  const int l31 = lane & 31, hi = lane >> 5;
  const int h16 = wm*16 + lk;

  // hoist Q fragments: head h16, d = dn*288 + ks*32 + lg*8
  bf16x8 qf[9];
  {
    const float* qb = &qfull[((size_t)b*H_ + h16)*DKV_ + dn*288 + lg*8];
    #pragma unroll
    for (int ks=0; ks<9; ++ks) {
      float4 u = ld4(qb + ks*32);
      float4 v = ld4(qb + ks*32 + 4);
      bf16x8 f;
      f[0]=f2b(u.x); f[1]=f2b(u.y); f[2]=f2b(u.z); f[3]=f2b(u.w);
      f[4]=f2b(v.x); f[5]=f2b(v.y); f[6]=f2b(v.z); f[7]=f2b(v.w);
      qf[ks] = f;
    }
  }

  // gather decomposition (thread-const)
  int row_l[9], coff_l[9], woff_l[9];
  #pragma unroll
  for (int l=0;l<9;l++) {
    int idx = t + l*256;                 // 16*144 = 2304 = 9*256
    int row = idx/144, c = idx - row*144;
    int d0 = c*4;
    row_l[l] = row; coff_l[l] = d0;
    woff_l[l] = (d0>>4)*DGSTR_ + row*16 + (d0&15);
  }
  const float* kvb = kv + (size_t)b*S_*DKV_;
  const int kbase = b*TOPK_ + kc*CHUNK_;
  tk_lds[t] = topk[kbase + t];
  __syncthreads();

  float4 stA[9], stB[9];
  #define ISSUE(ST, G) { \
    _Pragma("unroll") \
    for (int l=0;l<9;l++) { \
      int ki = tk_lds[(G)*TILE_ + row_l[l]]; \
      ST[l] = ld4(kvb + (size_t)ki*DKV_ + coff_l[l]); \
    } }
  #define WBUF(KB, ST) { \
    _Pragma("unroll") \
    for (int l=0;l<9;l++) { \
      short4 s4; s4.x=f2b(ST[l].x); s4.y=f2b(ST[l].y); s4.z=f2b(ST[l].z); s4.w=f2b(ST[l].w); \
      *reinterpret_cast<short4*>(&(KB)[woff_l[l]]) = s4; \
    } }

  // prologue: kr0 <- tile0; stA <- tile1; stB <- tile2 (3-deep)
  ISSUE(stA, 0);
  WBUF(krows[0], stA);
  ISSUE(stA, 1);
  ISSUE(stB, 2);
  asm volatile("s_waitcnt lgkmcnt(0)\n\ts_barrier" ::: "memory");

  float m_run = -INFINITY, l_run = 0.f;
  f32x16 acc[4];
  #pragma unroll
  for (int tt=0;tt<4;tt++)
    #pragma unroll
    for (int i=0;i<16;i++) acc[tt][i] = 0.f;

  const int soff = (dn*18 + (lg>>1))*DGSTR_ + lk*16 + (lg&1)*8;
  const int i15 = lk;
  const unsigned trc = (unsigned)((((wid*8) + ((lane>>4)&1))*DGSTR_ + (hi*8 + (i15>>2))*16 + (i15&3)*4)*2);

  for (int g=0; g<NG_; ++g) {
    const int cur = g & 1;
    short* kb = krows[cur];
    // ---- phase A: scores ----
    f32x4 sacc = {0.f,0.f,0.f,0.f};
    #pragma unroll
    for (int ks=0; ks<9; ++ks) {
      bf16x8 af = *reinterpret_cast<const bf16x8*>(&kb[soff + ks*(2*DGSTR_)]);
      sacc = __builtin_amdgcn_mfma_f32_16x16x32_bf16(af, qf[ks], sacc, 0, 0, 0);
    }
    #pragma unroll
    for (int r=0;r<4;r++)
      Spart[dn*528 + (lg*4+r)*33 + h16] = sacc[r];
    asm volatile("s_waitcnt lgkmcnt(0)\n\ts_barrier" ::: "memory");

    // ---- phase B: softmax + P/fl write + staged LDS write (tile g+1) + issue (tile g+3) ----
    float sfull[4];
    #pragma unroll
    for (int r=0;r<4;r++)
      sfull[r] = Spart[(lg*4+r)*33 + h16] + Spart[528 + (lg*4+r)*33 + h16];
    float tmax = fmaxf(fmaxf(sfull[0],sfull[1]), fmaxf(sfull[2],sfull[3]));
    tmax = fmaxf(tmax, __shfl_xor(tmax, 16));
    tmax = fmaxf(tmax, __shfl_xor(tmax, 32));
    float m_new = fmaxf(m_run, tmax);
    float fscale = __expf(m_run - m_new);
    m_run = m_new;
    float p0 = __expf(sfull[0]-m_new), p1 = __expf(sfull[1]-m_new);
    float p2 = __expf(sfull[2]-m_new), p3 = __expf(sfull[3]-m_new);
    float ps = (p0+p1)+(p2+p3);
    ps += __shfl_xor(ps, 16);
    ps += __shfl_xor(ps, 32);
    l_run = l_run*fscale + ps;
    if (dn==0) {
      short4 pk; pk.x=f2b(p0); pk.y=f2b(p1); pk.z=f2b(p2); pk.w=f2b(p3);
      *reinterpret_cast<short4*>(&P_lds[h16*VTS_ + lg*4]) = pk;
      if (lg==0) fl[h16] = fscale;
    }
    // tile t consumed at g=t-1, issued at g=t-3; parity of set matches g
    if ((g & 1) == 0) {
      if (g < NG_-1) WBUF(krows[cur^1], stA);
      if (g+3 < NG_) ISSUE(stA, g+3);
    } else {
      if (g < NG_-1) WBUF(krows[cur^1], stB);
      if (g+3 < NG_) ISSUE(stB, g+3);
    }
    asm volatile("s_waitcnt lgkmcnt(0)\n\ts_barrier" ::: "memory");

    // ---- phase C: PV via tr-read + 32x32x16 MFMA ----
    float fsc = fl[l31];
    bf16x8 pf = *reinterpret_cast<const bf16x8*>(&P_lds[l31*VTS_ + hi*8]);
    unsigned kaddr = (unsigned)(unsigned long long)(void*)kb;
    s16x4 tr0_0 = tr_read(kaddr + trc + 0*1056);
    s16x4 tr1_0 = tr_read(kaddr + trc + 0*1056 + 128);
    s16x4 tr0_1 = tr_read(kaddr + trc + 1*1056);
    s16x4 tr1_1 = tr_read(kaddr + trc + 1*1056 + 128);
    s16x4 tr0_2 = tr_read(kaddr + trc + 2*1056);
    s16x4 tr1_2 = tr_read(kaddr + trc + 2*1056 + 128);
    s16x4 tr0_3 = tr_read(kaddr + trc + 3*1056);
    s16x4 tr1_3 = tr_read(kaddr + trc + 3*1056 + 128);
    #pragma unroll
    for (int tt=0;tt<4;tt++)
      #pragma unroll
      for (int i=0;i<16;i++) acc[tt][i] *= fsc;
    asm volatile("s_waitcnt lgkmcnt(0)" ::: "memory");
    __builtin_amdgcn_sched_barrier(0);
    {
      bf16x8 vf;
      vf[0]=tr0_0[0]; vf[1]=tr0_0[1]; vf[2]=tr0_0[2]; vf[3]=tr0_0[3];
      vf[4]=tr1_0[0]; vf[5]=tr1_0[1]; vf[6]=tr1_0[2]; vf[7]=tr1_0[3];
      acc[0] = __builtin_amdgcn_mfma_f32_32x32x16_bf16(vf, pf, acc[0], 0, 0, 0);
      vf[0]=tr0_1[0]; vf[1]=tr0_1[1]; vf[2]=tr0_1[2]; vf[3]=tr0_1[3];
      vf[4]=tr1_1[0]; vf[5]=tr1_1[1]; vf[6]=tr1_1[2]; vf[7]=tr1_1[3];
      acc[1] = __builtin_amdgcn_mfma_f32_32x32x16_bf16(vf, pf, acc[1], 0, 0, 0);
      vf[0]=tr0_2[0]; vf[1]=tr0_2[1]; vf[2]=tr0_2[2]; vf[3]=tr0_2[3];
      vf[4]=tr1_2[0]; vf[5]=tr1_2[1]; vf[6]=tr1_2[2]; vf[7]=tr1_2[3];
      acc[2] = __builtin_amdgcn_mfma_f32_32x32x16_bf16(vf, pf, acc[2], 0, 0, 0);
      vf[0]=tr0_3[0]; vf[1]=tr0_3[1]; vf[2]=tr0_3[2]; vf[3]=tr0_3[3];
      vf[4]=tr1_3[0]; vf[5]=tr1_3[1]; vf[6]=tr1_3[2]; vf[7]=tr1_3[3];
      acc[3] = __builtin_amdgcn_mfma_f32_32x32x16_bf16(vf, pf, acc[3], 0, 0, 0);
    }
    // no barrier here: next phase A touches only krows[cur^1]/Spart.
  }

  if (dn==0 && lg==0) {
    om[(b*ACH_+kc)*H_ + h16] = m_run;
    ol[(b*ACH_+kc)*H_ + h16] = l_run;
  }
  #pragma unroll
  for (int tt=0;tt<4;tt++)
    #pragma unroll
    for (int q=0;q<4;q++) {
      float4 v = make_float4(acc[tt][4*q+0], acc[tt][4*q+1], acc[tt][4*q+2], acc[tt][4*q+3]);
      int r0 = wid*128 + tt*32 + 8*q + 4*hi;
      *reinterpret_cast<float4*>(&op[(((size_t)(b*ACH_+kc))*H_ + l31)*R_ + r0]) = v;
    }
  #undef ISSUE
  #undef WBUF
}

// ---------------- merge chunk partials ----------------
__global__ __launch_bounds__(128) void attn_merge(const float* __restrict__ om,
    const float* __restrict__ ol, const float* __restrict__ op, float* __restrict__ obuf) {
  const int bh = blockIdx.x;
  const int b = bh >> 5, h = bh & 31;
  const int t = threadIdx.x;
  float mv[8], lv[8], w[8];
  float M = -INFINITY;
  #pragma unroll
  for (int c=0;c<8;c++) { mv[c] = om[(b*ACH_+c)*H_ + h]; lv[c] = ol[(b*ACH_+c)*H_+h]; M = fmaxf(M, mv[c]); }
  float L = 0.f;
  #pragma unroll
  for (int c=0;c<8;c++) { w[c] = __expf(mv[c]-M); L += lv[c]*w[c]; }
  float inv = 1.0f / L;
  float4 s = make_float4(0.f,0.f,0.f,0.f);
  #pragma unroll
  for (int c=0;c<8;c++) {
    float4 v = ld4(&op[(((size_t)(b*ACH_+c))*H_ + h)*R_ + t*4]);
    s.x += v.x*w[c]; s.y += v.y*w[c]; s.z += v.z*w[c]; s.w += v.w*w[c];
  }
  s.x*=inv; s.y*=inv; s.z*=inv; s.w*=inv;
  *reinterpret_cast<float4*>(&obuf[((size_t)b*H_+h)*R_ + t*4]) = s;
}

// ---------------- final reduce of Wo partials ----------------
__global__ __launch_bounds__(256) void reduce_out(const float* __restrict__ op2, float* __restrict__ out) {
  int idx = blockIdx.x*256 + threadIdx.x; // float4 index
  float4 s = make_float4(0.f,0.f,0.f,0.f);
  #pragma unroll
  for (int c=0;c<KCH_;c++) {
    float4 v = ld4(&op2[(size_t)c*B_*HID_ + (size_t)idx*4]);
    s.x+=v.x; s.y+=v.y; s.z+=v.z; s.w+=v.w;
  }
  *reinterpret_cast<float4*>(&out[(size_t)idx*4]) = s;
}

extern "C" void kernel_launch(void* const* d_in, const int* in_sizes, int n_in,
                              void* d_out, int out_size, void* d_ws, size_t ws_size,
                              hipStream_t stream) {
  (void)in_sizes; (void)n_in; (void)out_size; (void)ws_size;
  const float* x   = (const float*)d_in[0];
  const float* Wq  = (const float*)d_in[1];
  const float* WK  = (const float*)d_in[2];
  const float* WKs = (const float*)d_in[3];
  const float* WV  = (const float*)d_in[4];
  const float* WVs = (const float*)d_in[5];
  const float* Wo  = (const float*)d_in[6];
  const float* kv  = (const float*)d_in[7];
  const int* topk  = (const int*)d_in[8];
  const int* pos   = (const int*)d_in[9];
  float* ws = (float*)d_ws;
  float* qp    = ws;                                   // 8*64*6144    = 3,145,728
  float* qn    = qp    + (size_t)8*64*6144;            // 64*32*128    =   262,144
  float* qfull = qn    + (size_t)64*32*128;            // 64*32*576    = 1,179,648
  float* om    = qfull + (size_t)64*32*576;            // 64*8*32
  float* ol    = om    + (size_t)64*8*32;              // 64*8*32
  float* op    = ol    + (size_t)64*8*32;              // 64*8*32*512  = 8,388,608
  float* obuf  = op    + (size_t)64*8*32*512;          // 64*32*512    = 1,048,576
  float* midp  = obuf  + (size_t)64*32*512;            // 2*64*4096    =   524,288
  float* op2   = midp  + (size_t)2*64*4096;            // 8*64*4096    = 2,097,152
  float* outf  = (float*)d_out;
  const float SC = 0.0721687836487032f; // 1/sqrt(192)

  gemm64_mfma<<<dim3(48,8),256,0,stream>>>(x, nullptr, Wq, qp, NQ_, HID_);
  reduce_rope<<<64,256,0,stream>>>(qp, pos, qn, qfull);
  // ql = q_nope @ W_K[h]^T * (WKs*SC) -> qfull[:, :, 0:512]
  gemm64x64_mfma<<<dim3(32,8,1),256,0,stream>>>(qn, NOPE_, WK, NOPE_, R_*NOPE_,
      WKs, SC, qfull, H_*DKV_, DKV_, 0, 1);
  attn_chunk<<<dim3(8,64),256,0,stream>>>(qfull, kv, topk, om, ol, op);
  attn_merge<<<2048,128,0,stream>>>(om, ol, op, obuf);
  // vproj partials: mid_p[kc] = o @ W_V[h]^T * WVs over K-half kc
  gemm64x64_mfma<<<dim3(32,2,2),256,0,stream>>>(obuf, R_, WV, R_, V_*R_,
      WVs, 1.0f, midp, HID_, V_, B_*HID_, 2);
  // out partials: (mid_p0 + mid_p1) @ Wo
  gemm64_mfma<<<dim3(32,8),256,0,stream>>>(midp, midp + (size_t)B_*HID_, Wo, op2, HID_, HID_);
  reduce_out<<<256,256,0,stream>>>(op2, outf);
}